// Round 5
// baseline (769.063 us; speedup 1.0000x reference)
//
#include <hip/hip_runtime.h>
#include <math.h>

#define B_ 8
#define C_ 256
#define N_ 9216
#define S_ 256
#define K_ 64
#define NCHUNK 36          // 9216 / 256
#define TILE_KS (K_ * S_)  // 16384

typedef unsigned short ushort_t;
typedef __attribute__((ext_vector_type(8))) short bf16x8;
typedef __attribute__((ext_vector_type(4))) float f32x4;

static __device__ inline ushort_t f2bf(float x) {
    unsigned int u = __float_as_uint(x);
    unsigned int r = (u + 0x7fffu + ((u >> 16) & 1u)) >> 16;
    return (ushort_t)r;
}

// ---------------- fold BN scale into W, convert to bf16; be[o] = b - m*s
__global__ __launch_bounds__(256) void prep_w(
    const float* __restrict__ phi_w, const float* __restrict__ phi_g, const float* __restrict__ phi_b,
    const float* __restrict__ phi_m, const float* __restrict__ phi_v,
    const float* __restrict__ th_w, const float* __restrict__ th_g, const float* __restrict__ th_b,
    const float* __restrict__ th_m, const float* __restrict__ th_v,
    const float* __restrict__ ro_w, const float* __restrict__ ro_g, const float* __restrict__ ro_b,
    const float* __restrict__ ro_m, const float* __restrict__ ro_v,
    const float* __restrict__ va_w, const float* __restrict__ va_g, const float* __restrict__ va_b,
    const float* __restrict__ va_m, const float* __restrict__ va_v,
    ushort_t* __restrict__ Wb, float* __restrict__ be)
{
    const int o = blockIdx.x;  // 0..831
    const int t = threadIdx.x; // = c
    const float *src, *g, *bb, *mm, *vv; int orel;
    if (o < 64)       { src = phi_w; g = phi_g; bb = phi_b; mm = phi_m; vv = phi_v; orel = o; }
    else if (o < 320) { src = th_w;  g = th_g;  bb = th_b;  mm = th_m;  vv = th_v;  orel = o - 64; }
    else if (o < 576) { src = ro_w;  g = ro_g;  bb = ro_b;  mm = ro_m;  vv = ro_v;  orel = o - 320; }
    else              { src = va_w;  g = va_g;  bb = va_b;  mm = va_m;  vv = va_v;  orel = o - 576; }
    const float s = g[orel] / sqrtf(vv[orel] + 1e-5f);
    Wb[o * C_ + t] = f2bf(src[orel * C_ + t] * s);
    if (t == 0) be[o] = bb[orel] - mm[orel] * s;
}

// ---------------- X[b][c][n] fp32 -> Xb[b][n][c] bf16 (64x64 tiles via LDS)
__global__ __launch_bounds__(256) void xpose(
    const float* __restrict__ X, ushort_t* __restrict__ Xb)
{
    __shared__ float T[64][65];
    const int b = blockIdx.z, c0 = blockIdx.y * 64, n0 = blockIdx.x * 64;
    const int t = threadIdx.x;
#pragma unroll
    for (int p = 0; p < 4; ++p) {
        int c = p * 16 + (t >> 4), nn = (t & 15) * 4;
        float4 v = *(const float4*)&X[((size_t)b * C_ + c0 + c) * N_ + n0 + nn];
        T[c][nn] = v.x; T[c][nn + 1] = v.y; T[c][nn + 2] = v.z; T[c][nn + 3] = v.w;
    }
    __syncthreads();
#pragma unroll
    for (int p = 0; p < 4; ++p) {
        int nn = p * 16 + (t >> 4), cl = (t & 15) * 4;
        ushort4 u;
        u.x = f2bf(T[cl][nn]); u.y = f2bf(T[cl + 1][nn]);
        u.z = f2bf(T[cl + 2][nn]); u.w = f2bf(T[cl + 3][nn]);
        *(ushort4*)&Xb[((size_t)b * N_ + n0 + nn) * C_ + c0 + cl] = u;
    }
}

// ---------------- fused bf16-MFMA projection: out = relu(Wb . x + be)
// block: [64 o] x [256 n]; 4 waves, each [64 o][64 n]; K=256 in 4 stages of 64
__global__ __launch_bounds__(256) void proj_mfma(
    const ushort_t* __restrict__ Wb, const float* __restrict__ be,
    const ushort_t* __restrict__ Xb,
    float* __restrict__ out0, float* __restrict__ out1,
    int phase_base, int o_split, int osz0, int osz1)
{
    __shared__ short sm[32768];  // 64 KB: W cells [0,2048), X cells [2048,4096) (16B cells)
    const int t = threadIdx.x;
    const int l = t & 63, w = t >> 6;
    const int b = blockIdx.x / 36;
    const int n0 = (blockIdx.x % 36) * 256;
    const int o0 = phase_base + blockIdx.y * 64;  // absolute o

    const uint4* Wv = (const uint4*)Wb;
    const uint4* Xv = (const uint4*)Xb;
    uint4* smv = (uint4*)sm;

    // --- stage W (full K) + X stage 0
    uint4 wreg[8], xreg[8];
#pragma unroll
    for (int i = 0; i < 8; ++i) {
        int cell = i * 256 + t;
        int osub = cell >> 9, g = (cell >> 4) & 31, oi = cell & 15;
        wreg[i] = Wv[(size_t)(o0 + osub * 16 + oi) * 32 + g];
    }
#pragma unroll
    for (int i = 0; i < 8; ++i) {
        int cell = i * 256 + t;
        int s = cell >> 7, g8 = (cell >> 4) & 7, ni = cell & 15;
        xreg[i] = Xv[(size_t)(b * N_ + n0 + s * 16 + ni) * 32 + g8];
    }
#pragma unroll
    for (int i = 0; i < 8; ++i) smv[i * 256 + t] = wreg[i];
#pragma unroll
    for (int i = 0; i < 8; ++i) smv[2048 + i * 256 + t] = xreg[i];
    __syncthreads();

    f32x4 zr = {0.f, 0.f, 0.f, 0.f};
    f32x4 acc[4][4];
#pragma unroll
    for (int i = 0; i < 4; ++i)
#pragma unroll
        for (int j = 0; j < 4; ++j) acc[i][j] = zr;

    const bf16x8* smW = (const bf16x8*)sm;
    const bf16x8* smX = (const bf16x8*)(sm + 16384);

    for (int st = 0; st < 4; ++st) {
        if (st < 3) {  // early-issue next stage's global loads (hide under MFMA)
#pragma unroll
            for (int i = 0; i < 8; ++i) {
                int cell = i * 256 + t;
                int s = cell >> 7, g8 = (cell >> 4) & 7, ni = cell & 15;
                xreg[i] = Xv[(size_t)(b * N_ + n0 + s * 16 + ni) * 32 + (st + 1) * 8 + g8];
            }
        }
#pragma unroll
        for (int kgl = 0; kgl < 2; ++kgl) {
            const int kg = st * 2 + kgl;
            bf16x8 A[4], Bf[4];
#pragma unroll
            for (int os = 0; os < 4; ++os)
                A[os] = smW[(os * 32 + kg * 4 + (l >> 4)) * 16 + (l & 15)];
#pragma unroll
            for (int j = 0; j < 4; ++j)
                Bf[j] = smX[((w * 4 + j) * 8 + kgl * 4 + (l >> 4)) * 16 + (l & 15)];
#pragma unroll
            for (int os = 0; os < 4; ++os)
#pragma unroll
                for (int j = 0; j < 4; ++j)
                    acc[os][j] = __builtin_amdgcn_mfma_f32_16x16x32_bf16(A[os], Bf[j], acc[os][j], 0, 0, 0);
        }
        __syncthreads();
        if (st < 3) {
#pragma unroll
            for (int i = 0; i < 8; ++i) smv[2048 + i * 256 + t] = xreg[i];
            __syncthreads();
        }
    }

    // --- epilogue: relu(acc + be), LDS-transpose per wave, NONTEMPORAL float4 stores.
    // R4 showed WRITE amplification is invariant to store shape -> hypothesis: L2/L3 churn.
    // NT stores stream the (never-re-written) outputs past L2, also protecting cached Xb.
    const int ob = o0 - phase_base;
    float* dst; int od, osz;
    if (ob < o_split) { dst = out0; od = ob;           osz = osz0; }
    else              { dst = out1; od = ob - o_split; osz = osz1; }
    float* Tw = (float*)sm + w * 2176;  // 32 rows x 68 floats per wave
#pragma unroll
    for (int half = 0; half < 2; ++half) {
        __syncthreads();
#pragma unroll
        for (int osl = 0; osl < 2; ++osl) {
            const int os = half * 2 + osl;
#pragma unroll
            for (int r = 0; r < 4; ++r) {
                const int orow = os * 16 + (l >> 4) * 4 + r;  // 0..63 within tile
                const int lrow = orow - half * 32;            // 0..31
                const float bias = be[o0 + orow];
#pragma unroll
                for (int j = 0; j < 4; ++j)
                    Tw[lrow * 68 + j * 16 + (l & 15)] = fmaxf(acc[os][j][r] + bias, 0.f);
            }
        }
        __syncthreads();
#pragma unroll
        for (int i = 0; i < 8; ++i) {
            const int lrow = i * 4 + (l >> 4);   // 0..31
            const int orow = half * 32 + lrow;
            f32x4 v = *(const f32x4*)&Tw[lrow * 68 + (l & 15) * 4];
            __builtin_nontemporal_store(v,
                (f32x4*)&dst[((size_t)b * osz + od + orow) * N_ + n0 + w * 64 + (l & 15) * 4]);
        }
    }
}

// ---------------- per-row (length N) softmax stats: max and 1/sum(exp(x-max))
__global__ __launch_bounds__(256) void rowstat_n(
    const float* __restrict__ T, float* __restrict__ stmax, float* __restrict__ stinv)
{
    const int row = blockIdx.x;  // b*S + s
    const float* p = T + (size_t)row * N_;
    const int t = threadIdx.x;
    float v[36];
    float mx = -INFINITY;
#pragma unroll
    for (int i = 0; i < 36; ++i) { v[i] = p[t + i * 256]; mx = fmaxf(mx, v[i]); }
    __shared__ float red[256];
    red[t] = mx; __syncthreads();
    for (int s2 = 128; s2 > 0; s2 >>= 1) {
        if (t < s2) red[t] = fmaxf(red[t], red[t + s2]);
        __syncthreads();
    }
    mx = red[0]; __syncthreads();
    float sum = 0.f;
#pragma unroll
    for (int i = 0; i < 36; ++i) sum += __expf(v[i] - mx);
    red[t] = sum; __syncthreads();
    for (int s2 = 128; s2 > 0; s2 >>= 1) {
        if (t < s2) red[t] += red[t + s2];
        __syncthreads();
    }
    if (t == 0) { stmax[row] = mx; stinv[row] = 1.0f / red[0]; }
}

// ---------------- P[chunk][b][k][s] = sum_{n in chunk} A[b,k,n] * softmax?(Bm)[b,s,n]
__global__ __launch_bounds__(256) void ks_gemm_part(
    const float* __restrict__ A, const float* __restrict__ Bm,
    const float* __restrict__ stmax, const float* __restrict__ stinv,
    float* __restrict__ P)
{
    __shared__ float th[S_][33];
    __shared__ float ph[K_][33];
    const int b = blockIdx.y;
    const int nc0 = blockIdx.x * 256;
    const int t = threadIdx.x;
    const int lane = t & 63;
    const int k0 = (t >> 6) * 16;
    const int ln = t & 31, lr = t >> 5;
    float acc[4][16];
#pragma unroll
    for (int si = 0; si < 4; ++si)
#pragma unroll
        for (int ki = 0; ki < 16; ++ki) acc[si][ki] = 0.f;

    for (int sub = 0; sub < 8; ++sub) {
        const int n0 = nc0 + sub * 32;
        __syncthreads();
#pragma unroll
        for (int i = 0; i < 32; ++i) {
            const int row = lr + 8 * i;
            float raw = Bm[((size_t)b * S_ + row) * N_ + n0 + ln];
            th[row][ln] = stmax ? __expf(raw - stmax[b * S_ + row]) * stinv[b * S_ + row] : raw;
        }
#pragma unroll
        for (int i = 0; i < 8; ++i)
            ph[lr + 8 * i][ln] = A[((size_t)b * K_ + lr + 8 * i) * N_ + n0 + ln];
        __syncthreads();
#pragma unroll 4
        for (int n = 0; n < 32; ++n) {
            float tv[4];
#pragma unroll
            for (int si = 0; si < 4; ++si) tv[si] = th[lane + 64 * si][n];
#pragma unroll
            for (int kg = 0; kg < 4; ++kg) {
                float p0 = ph[k0 + 4 * kg + 0][n];
                float p1 = ph[k0 + 4 * kg + 1][n];
                float p2 = ph[k0 + 4 * kg + 2][n];
                float p3 = ph[k0 + 4 * kg + 3][n];
#pragma unroll
                for (int si = 0; si < 4; ++si) {
                    acc[si][4 * kg + 0] = fmaf(tv[si], p0, acc[si][4 * kg + 0]);
                    acc[si][4 * kg + 1] = fmaf(tv[si], p1, acc[si][4 * kg + 1]);
                    acc[si][4 * kg + 2] = fmaf(tv[si], p2, acc[si][4 * kg + 2]);
                    acc[si][4 * kg + 3] = fmaf(tv[si], p3, acc[si][4 * kg + 3]);
                }
            }
        }
    }
    float* Pb = P + ((size_t)blockIdx.x * B_ + b) * TILE_KS;
#pragma unroll
    for (int si = 0; si < 4; ++si)
#pragma unroll
        for (int ki = 0; ki < 16; ++ki)
            Pb[(k0 + ki) * S_ + lane + 64 * si] = acc[si][ki];
}

// ---------------- out[i] = sum_c P[c][i]
__global__ __launch_bounds__(256) void chunk_reduce(
    const float* __restrict__ P, float* __restrict__ out)
{
    const int i = blockIdx.x * 256 + threadIdx.x;
    float s = 0.f;
#pragma unroll
    for (int c = 0; c < NCHUNK; ++c) s += P[(size_t)c * (B_ * TILE_KS) + i];
    out[i] = s;
}

// ---------------- QT[b,k,n] = sum_s D[b,k,s] * softmax_s(rou)[b,s,n]; nrm2 partials fused
__global__ __launch_bounds__(256) void q_raw_fused(
    const float* __restrict__ D, const float* __restrict__ Rou,
    float* __restrict__ QT, float* __restrict__ Nrm)
{
    __shared__ float dl[K_ * S_];  // 64KB
    const int b = blockIdx.y;
    const int n0 = blockIdx.x * 256;
    const int t = threadIdx.x;
    const float* Db = D + (size_t)b * K_ * S_;
#pragma unroll
    for (int i = 0; i < 64; ++i) dl[t + 256 * i] = Db[t + 256 * i];
    // column softmax stats (softmax over S at this n) -- replaces softmax_s kernel
    const int n = n0 + t;
    const float* Rb = Rou + (size_t)b * S_ * N_ + n;
    float mx = -INFINITY;
    for (int s = 0; s < S_; ++s) mx = fmaxf(mx, Rb[(size_t)s * N_]);
    float sum = 0.f;
    for (int s = 0; s < S_; ++s) sum += __expf(Rb[(size_t)s * N_] - mx);
    const float inv = 1.0f / sum;
    __syncthreads();
    float acc[64];
#pragma unroll
    for (int k = 0; k < 64; ++k) acc[k] = 0.f;
    for (int sg = 0; sg < 64; ++sg) {
        float r0 = __expf(Rb[(size_t)(4 * sg + 0) * N_] - mx) * inv;
        float r1 = __expf(Rb[(size_t)(4 * sg + 1) * N_] - mx) * inv;
        float r2 = __expf(Rb[(size_t)(4 * sg + 2) * N_] - mx) * inv;
        float r3 = __expf(Rb[(size_t)(4 * sg + 3) * N_] - mx) * inv;
#pragma unroll
        for (int k = 0; k < 64; ++k) {
            float4 d4 = *(const float4*)&dl[k * 256 + 4 * sg];
            acc[k] = fmaf(d4.x, r0, fmaf(d4.y, r1, fmaf(d4.z, r2, fmaf(d4.w, r3, acc[k]))));
        }
    }
#pragma unroll
    for (int k = 0; k < 64; ++k)
        QT[((size_t)b * K_ + k) * N_ + n] = acc[k];
    // nrm2[b,k] partials: reuse dl as [32][257] (padded, conflict-free both sides)
#pragma unroll
    for (int h = 0; h < 2; ++h) {
        __syncthreads();
#pragma unroll
        for (int kk = 0; kk < 32; ++kk) {
            float a = acc[h * 32 + kk];
            dl[kk * 257 + t] = a * a;
        }
        __syncthreads();
        if (t < 32) {
            float ss = 0.f;
            for (int j = 0; j < 256; ++j) ss += dl[t * 257 + j];
            atomicAdd(&Nrm[b * K_ + h * 32 + t], ss);
        }
    }
}

// ---------------- QT = softmax_k(QT / max(sqrt(nrm2),eps)) in place; Qout transposed copy; qsum fused
__global__ __launch_bounds__(256) void q_final(
    float* __restrict__ QT, const float* __restrict__ Nrm,
    float* __restrict__ Qout, float* __restrict__ Qs)
{
    __shared__ float T[64][65];
    __shared__ float invn[64];
    const int b = blockIdx.y;
    const int n0 = blockIdx.x * 256;
    const int t = threadIdx.x;
    if (t < 64) invn[t] = 1.0f / fmaxf(sqrtf(Nrm[b * K_ + t]), 1e-12f);
    __syncthreads();
    const int n = n0 + t;
    float q[64];
    float mx = -INFINITY;
#pragma unroll
    for (int k = 0; k < 64; ++k) {
        q[k] = QT[((size_t)b * K_ + k) * N_ + n] * invn[k];
        mx = fmaxf(mx, q[k]);
    }
    float sum = 0.f;
#pragma unroll
    for (int k = 0; k < 64; ++k) { q[k] = __expf(q[k] - mx); sum += q[k]; }
    const float inv = 1.0f / sum;
#pragma unroll
    for (int k = 0; k < 64; ++k) {
        q[k] *= inv;
        QT[((size_t)b * K_ + k) * N_ + n] = q[k];
    }
    float ksm = 0.f;
    for (int g = 0; g < 4; ++g) {
        __syncthreads();
        if ((t >> 6) == g) {
#pragma unroll
            for (int k = 0; k < 64; ++k) T[t & 63][k] = q[k];
        }
        __syncthreads();
        float* dst = Qout + ((size_t)b * N_ + n0 + 64 * g) * K_;
#pragma unroll
        for (int j = 0; j < 4; ++j) {
            int p = j * 1024 + t * 4;
            f32x4 v = *(const f32x4*)&T[p >> 6][p & 63];
            __builtin_nontemporal_store(v, (f32x4*)&dst[p]);
        }
        if (t < 64) {  // qsum partial: column t of this 64n x 64k tile
            for (int nn = 0; nn < 64; ++nn) ksm += T[nn][t];
        }
    }
    if (t < 64) atomicAdd(&Qs[b * K_ + t], ksm);
}

// ---------------- Z[b,s,k] = l2norm_s(ZnT[b,k,s] / qsum[b,k])
__global__ __launch_bounds__(256) void z_final(
    const float* __restrict__ ZnT, const float* __restrict__ Qs, float* __restrict__ Z)
{
    __shared__ float red[256];
    __shared__ float invn[64];
    const int b = blockIdx.x;
    const int t = threadIdx.x;
    const float* Zb = ZnT + (size_t)b * K_ * S_;
    {
        const int k = t >> 2, qq = t & 3;
        const float invq = 1.0f / Qs[b * K_ + k];
        float ss = 0.f;
        for (int j = 0; j < 64; ++j) {
            float v = Zb[k * S_ + qq * 64 + j] * invq;
            ss = fmaf(v, v, ss);
        }
        red[t] = ss;
    }
    __syncthreads();
    if ((t & 3) == 0) {
        float tot = red[t] + red[t + 1] + red[t + 2] + red[t + 3];
        invn[t >> 2] = 1.0f / fmaxf(sqrtf(tot), 1e-12f);
    }
    __syncthreads();
    {
        const int k = t & 63, w = t >> 6;
        const float sc = invn[k] / Qs[b * K_ + k];
        for (int j = 0; j < 64; ++j) {
            int s = w * 64 + j;
            Z[((size_t)b * S_ + s) * K_ + k] = Zb[k * S_ + s] * sc;
        }
    }
}

extern "C" void kernel_launch(void* const* d_in, const int* in_sizes, int n_in,
                              void* d_out, int out_size, void* d_ws, size_t ws_size,
                              hipStream_t stream)
{
    const float* X       = (const float*)d_in[0];
    const float* phi_w   = (const float*)d_in[1];
    const float* phi_g   = (const float*)d_in[2];
    const float* phi_b   = (const float*)d_in[3];
    const float* phi_m   = (const float*)d_in[4];
    const float* phi_v   = (const float*)d_in[5];
    const float* theta_w = (const float*)d_in[6];
    const float* theta_g = (const float*)d_in[7];
    const float* theta_b = (const float*)d_in[8];
    const float* theta_m = (const float*)d_in[9];
    const float* theta_v = (const float*)d_in[10];
    const float* rou_w   = (const float*)d_in[11];
    const float* rou_g   = (const float*)d_in[12];
    const float* rou_b   = (const float*)d_in[13];
    const float* rou_m   = (const float*)d_in[14];
    const float* rou_v   = (const float*)d_in[15];
    const float* val_w   = (const float*)d_in[16];
    const float* val_g   = (const float*)d_in[17];
    const float* val_b   = (const float*)d_in[18];
    const float* val_m   = (const float*)d_in[19];
    const float* val_v   = (const float*)d_in[20];

    float* ws = (float*)d_ws;
    size_t off = 0;
    ushort_t* Xb = (ushort_t*)(ws + off); off += (size_t)B_ * N_ * C_ / 2;   // bf16 [b][n][c]
    ushort_t* Wb = (ushort_t*)(ws + off); off += 832 * C_ / 2;               // bf16 [832][256]
    float* be    = ws + off; off += 832;
    float* stmax = ws + off; off += B_ * S_;                // theta row max
    float* stinv = ws + off; off += B_ * S_;                // theta row 1/sum
    float* xphi  = ws + off; off += (size_t)B_ * K_ * N_;   // phi; later QT alias
    float* xth   = ws + off; off += (size_t)B_ * S_ * N_;   // theta; later val
    float* xrou  = ws + off; off += (size_t)B_ * S_ * N_;   // rou (raw)
    float* part  = ws + off; off += (size_t)NCHUNK * B_ * TILE_KS;
    float* disc  = ws + off; off += (size_t)B_ * K_ * S_;
    float* znumT = ws + off; off += (size_t)B_ * K_ * S_;
    float* nrm2  = ws + off; off += B_ * K_;
    float* qsum  = ws + off; off += B_ * K_;

    float* QT = xphi;

    float* Zout = (float*)d_out;                       // B*S*K
    float* Qout = Zout + (size_t)B_ * S_ * K_;         // B*N*K

    // zero the atomic accumulators (nrm2+qsum contiguous)
    hipMemsetAsync(nrm2, 0, 2 * B_ * K_ * sizeof(float), stream);

    prep_w<<<832, 256, 0, stream>>>(phi_w, phi_g, phi_b, phi_m, phi_v,
                                    theta_w, theta_g, theta_b, theta_m, theta_v,
                                    rou_w, rou_g, rou_b, rou_m, rou_v,
                                    val_w, val_g, val_b, val_m, val_v, Wb, be);
    xpose<<<dim3(N_ / 64, C_ / 64, B_), 256, 0, stream>>>(X, Xb);

    // phase A: o in [0,320): phi (64 rows) + theta (256 rows)
    proj_mfma<<<dim3(36 * B_, 5), 256, 0, stream>>>(Wb, be, Xb, xphi, xth, 0, 64, K_, S_);
    rowstat_n<<<B_ * S_, 256, 0, stream>>>(xth, stmax, stinv);
    ks_gemm_part<<<dim3(NCHUNK, B_), 256, 0, stream>>>(xphi, xth, stmax, stinv, part);
    chunk_reduce<<<B_ * TILE_KS / 256, 256, 0, stream>>>(part, disc);

    // phase B: o in [320,832): rou (256 rows) + val (256 rows, into xth)
    proj_mfma<<<dim3(36 * B_, 8), 256, 0, stream>>>(Wb, be, Xb, xrou, xth, 320, 256, S_, S_);
    q_raw_fused<<<dim3(N_ / 256, B_), 256, 0, stream>>>(disc, xrou, QT, nrm2);
    q_final<<<dim3(N_ / 256, B_), 256, 0, stream>>>(QT, nrm2, Qout, qsum);
    ks_gemm_part<<<dim3(NCHUNK, B_), 256, 0, stream>>>(QT, xth, (const float*)nullptr, (const float*)nullptr, part);
    chunk_reduce<<<B_ * TILE_KS / 256, 256, 0, stream>>>(part, znumT);
    z_final<<<B_, 256, 0, stream>>>(znumT, qsum, Zout);
}

// Round 6
// 353.420 us; speedup vs baseline: 2.1761x; 2.1761x over previous
//
#include <hip/hip_runtime.h>
#include <math.h>

#define B_ 8
#define C_ 256
#define N_ 9216
#define S_ 256
#define K_ 64
#define NCHUNK 36            // 9216 / 256
#define TILE_KS (K_ * S_)    // 16384
#define NC8 (N_ / 8)         // 1152 16B-cells per [*][N] bf16 row

typedef unsigned short ushort_t;
typedef __attribute__((ext_vector_type(8))) short bf16x8;
typedef __attribute__((ext_vector_type(4))) float f32x4;

static __device__ inline ushort_t f2bf(float x) {
    unsigned int u = __float_as_uint(x);
    unsigned int r = (u + 0x7fffu + ((u >> 16) & 1u)) >> 16;
    return (ushort_t)r;
}
static __device__ inline float bf2f(ushort_t u) {
    return __uint_as_float(((unsigned int)u) << 16);
}

// exp-weight one 8-bf16 cell (row-constant max/invsum in s)
static __device__ inline uint4 expcell(uint4 u, float2 s) {
    uint4 r;
    unsigned int* up = (unsigned int*)&u;
    unsigned int* rp = (unsigned int*)&r;
#pragma unroll
    for (int q = 0; q < 4; ++q) {
        unsigned int x = up[q];
        float lo = __uint_as_float((x & 0xffffu) << 16);
        float hi = __uint_as_float(x & 0xffff0000u);
        float el = __expf(lo - s.x) * s.y;
        float eh = __expf(hi - s.x) * s.y;
        rp[q] = (unsigned int)f2bf(el) | ((unsigned int)f2bf(eh) << 16);
    }
    return r;
}

// ---------------- fold BN scale into W, convert to bf16; be[o] = b - m*s
__global__ __launch_bounds__(256) void prep_w(
    const float* __restrict__ phi_w, const float* __restrict__ phi_g, const float* __restrict__ phi_b,
    const float* __restrict__ phi_m, const float* __restrict__ phi_v,
    const float* __restrict__ th_w, const float* __restrict__ th_g, const float* __restrict__ th_b,
    const float* __restrict__ th_m, const float* __restrict__ th_v,
    const float* __restrict__ ro_w, const float* __restrict__ ro_g, const float* __restrict__ ro_b,
    const float* __restrict__ ro_m, const float* __restrict__ ro_v,
    const float* __restrict__ va_w, const float* __restrict__ va_g, const float* __restrict__ va_b,
    const float* __restrict__ va_m, const float* __restrict__ va_v,
    ushort_t* __restrict__ Wb, float* __restrict__ be)
{
    const int o = blockIdx.x;  // 0..831
    const int t = threadIdx.x; // = c
    const float *src, *g, *bb, *mm, *vv; int orel;
    if (o < 64)       { src = phi_w; g = phi_g; bb = phi_b; mm = phi_m; vv = phi_v; orel = o; }
    else if (o < 320) { src = th_w;  g = th_g;  bb = th_b;  mm = th_m;  vv = th_v;  orel = o - 64; }
    else if (o < 576) { src = ro_w;  g = ro_g;  bb = ro_b;  mm = ro_m;  vv = ro_v;  orel = o - 320; }
    else              { src = va_w;  g = va_g;  bb = va_b;  mm = va_m;  vv = va_v;  orel = o - 576; }
    const float s = g[orel] / sqrtf(vv[orel] + 1e-5f);
    Wb[o * C_ + t] = f2bf(src[orel * C_ + t] * s);
    if (t == 0) be[o] = bb[orel] - mm[orel] * s;
}

// ---------------- X[b][c][n] fp32 -> Xb[b][n][c] bf16
__global__ __launch_bounds__(256) void xpose(
    const float* __restrict__ X, ushort_t* __restrict__ Xb)
{
    __shared__ float T[64][65];
    const int b = blockIdx.z, c0 = blockIdx.y * 64, n0 = blockIdx.x * 64;
    const int t = threadIdx.x;
#pragma unroll
    for (int p = 0; p < 4; ++p) {
        int c = p * 16 + (t >> 4), nn = (t & 15) * 4;
        float4 v = *(const float4*)&X[((size_t)b * C_ + c0 + c) * N_ + n0 + nn];
        T[c][nn] = v.x; T[c][nn + 1] = v.y; T[c][nn + 2] = v.z; T[c][nn + 3] = v.w;
    }
    __syncthreads();
#pragma unroll
    for (int p = 0; p < 4; ++p) {
        int nn = p * 16 + (t >> 4), cl = (t & 15) * 4;
        ushort4 u;
        u.x = f2bf(T[cl][nn]); u.y = f2bf(T[cl + 1][nn]);
        u.z = f2bf(T[cl + 2][nn]); u.w = f2bf(T[cl + 3][nn]);
        *(ushort4*)&Xb[((size_t)b * N_ + n0 + nn) * C_ + c0 + cl] = u;
    }
}

// ---------------- fused bf16-MFMA projection, ALL 13 o-tiles, bf16 outputs.
// phi/theta/val: row-major [o][n]; rou: transposed [n][s] (feeds row-softmax + QT GEMM).
__global__ __launch_bounds__(256) void proj_mfma_all(
    const ushort_t* __restrict__ Wb, const float* __restrict__ be,
    const ushort_t* __restrict__ Xb,
    ushort_t* __restrict__ Pbf, ushort_t* __restrict__ Tbf,
    ushort_t* __restrict__ Vbf, ushort_t* __restrict__ Rt)
{
    __shared__ short sm[32768];  // 64 KB
    const int t = threadIdx.x;
    const int l = t & 63, w = t >> 6;
    const int b = blockIdx.x / 36;
    const int n0 = (blockIdx.x % 36) * 256;
    const int o0 = blockIdx.y * 64;

    const uint4* Wv = (const uint4*)Wb;
    const uint4* Xv = (const uint4*)Xb;
    uint4* smv = (uint4*)sm;

    uint4 wreg[8], xreg[8];
#pragma unroll
    for (int i = 0; i < 8; ++i) {
        int cell = i * 256 + t;
        int osub = cell >> 9, g = (cell >> 4) & 31, oi = cell & 15;
        wreg[i] = Wv[(size_t)(o0 + osub * 16 + oi) * 32 + g];
    }
#pragma unroll
    for (int i = 0; i < 8; ++i) {
        int cell = i * 256 + t;
        int s = cell >> 7, g8 = (cell >> 4) & 7, ni = cell & 15;
        xreg[i] = Xv[(size_t)(b * N_ + n0 + s * 16 + ni) * 32 + g8];
    }
#pragma unroll
    for (int i = 0; i < 8; ++i) smv[i * 256 + t] = wreg[i];
#pragma unroll
    for (int i = 0; i < 8; ++i) smv[2048 + i * 256 + t] = xreg[i];
    __syncthreads();

    f32x4 zr = {0.f, 0.f, 0.f, 0.f};
    f32x4 acc[4][4];
#pragma unroll
    for (int i = 0; i < 4; ++i)
#pragma unroll
        for (int j = 0; j < 4; ++j) acc[i][j] = zr;

    const bf16x8* smW = (const bf16x8*)sm;
    const bf16x8* smX = (const bf16x8*)(sm + 16384);

    for (int st = 0; st < 4; ++st) {
        if (st < 3) {
#pragma unroll
            for (int i = 0; i < 8; ++i) {
                int cell = i * 256 + t;
                int s = cell >> 7, g8 = (cell >> 4) & 7, ni = cell & 15;
                xreg[i] = Xv[(size_t)(b * N_ + n0 + s * 16 + ni) * 32 + (st + 1) * 8 + g8];
            }
        }
#pragma unroll
        for (int kgl = 0; kgl < 2; ++kgl) {
            const int kg = st * 2 + kgl;
            bf16x8 A[4], Bf[4];
#pragma unroll
            for (int os = 0; os < 4; ++os)
                A[os] = smW[(os * 32 + kg * 4 + (l >> 4)) * 16 + (l & 15)];
#pragma unroll
            for (int j = 0; j < 4; ++j)
                Bf[j] = smX[((w * 4 + j) * 8 + kgl * 4 + (l >> 4)) * 16 + (l & 15)];
#pragma unroll
            for (int os = 0; os < 4; ++os)
#pragma unroll
                for (int j = 0; j < 4; ++j)
                    acc[os][j] = __builtin_amdgcn_mfma_f32_16x16x32_bf16(A[os], Bf[j], acc[os][j], 0, 0, 0);
        }
        __syncthreads();
        if (st < 3) {
#pragma unroll
            for (int i = 0; i < 8; ++i) smv[2048 + i * 256 + t] = xreg[i];
            __syncthreads();
        }
    }

    // epilogue (block-uniform branch on o0)
    if (o0 >= 320 && o0 < 576) {
        // rou -> Rt[b][n][256s] (transposed), per-wave [64n][72pad] bf16 tile
        const int od = o0 - 320;
        ushort_t* Tt = (ushort_t*)sm + w * (64 * 72);
        __syncthreads();
#pragma unroll
        for (int os = 0; os < 4; ++os)
#pragma unroll
            for (int r = 0; r < 4; ++r) {
                const int scol = os * 16 + (l >> 4) * 4 + r;
                const float bias = be[o0 + scol];
#pragma unroll
                for (int j = 0; j < 4; ++j)
                    Tt[(j * 16 + (l & 15)) * 72 + scol] = f2bf(fmaxf(acc[os][j][r] + bias, 0.f));
            }
        __syncthreads();
#pragma unroll
        for (int p = 0; p < 8; ++p) {
            const int row = p * 8 + (l >> 3);
            uint4 v = *(const uint4*)&Tt[row * 72 + (l & 7) * 8];
            *(uint4*)&Rt[((size_t)b * N_ + n0 + w * 64 + row) * 256 + od + (l & 7) * 8] = v;
        }
    } else {
        ushort_t* dst; int od, osz;
        if (o0 < 64)       { dst = Pbf; od = o0;       osz = 64;  }
        else if (o0 < 320) { dst = Tbf; od = o0 - 64;  osz = 256; }
        else               { dst = Vbf; od = o0 - 576; osz = 256; }
        ushort_t* Tw = (ushort_t*)sm + w * (32 * 68);
#pragma unroll
        for (int half = 0; half < 2; ++half) {
            __syncthreads();
#pragma unroll
            for (int osl = 0; osl < 2; ++osl) {
                const int os = half * 2 + osl;
#pragma unroll
                for (int r = 0; r < 4; ++r) {
                    const int lrow = osl * 16 + (l >> 4) * 4 + r;
                    const int orow = half * 32 + lrow;
                    const float bias = be[o0 + orow];
#pragma unroll
                    for (int j = 0; j < 4; ++j)
                        Tw[lrow * 68 + j * 16 + (l & 15)] = f2bf(fmaxf(acc[os][j][r] + bias, 0.f));
                }
            }
            __syncthreads();
#pragma unroll
            for (int i = 0; i < 8; ++i) {
                const int lrow = i * 4 + (l >> 4);
                ushort4 v = *(const ushort4*)&Tw[lrow * 68 + (l & 15) * 4];
                *(ushort4*)&dst[((size_t)(b * osz + od + half * 32 + lrow)) * N_ + n0 + w * 64 + (l & 15) * 4] = v;
            }
        }
    }
}

// ---------------- theta row stats: st2[row] = (max, 1/sum(exp(x-max))) over N
__global__ __launch_bounds__(256) void rowstat_n(
    const ushort_t* __restrict__ T, float* __restrict__ st2)
{
    const int row = blockIdx.x;  // b*256 + s
    const ushort4* p = (const ushort4*)(T + (size_t)row * N_);
    const int t = threadIdx.x;
    float v[36];
    float mx = -INFINITY;
#pragma unroll
    for (int i = 0; i < 9; ++i) {
        ushort4 u = p[t + i * 256];
        v[i * 4 + 0] = bf2f(u.x); v[i * 4 + 1] = bf2f(u.y);
        v[i * 4 + 2] = bf2f(u.z); v[i * 4 + 3] = bf2f(u.w);
        mx = fmaxf(mx, fmaxf(fmaxf(v[i * 4], v[i * 4 + 1]), fmaxf(v[i * 4 + 2], v[i * 4 + 3])));
    }
    __shared__ float red[256];
    red[t] = mx; __syncthreads();
    for (int s2 = 128; s2 > 0; s2 >>= 1) {
        if (t < s2) red[t] = fmaxf(red[t], red[t + s2]);
        __syncthreads();
    }
    mx = red[0]; __syncthreads();
    float sum = 0.f;
#pragma unroll
    for (int i = 0; i < 36; ++i) sum += __expf(v[i] - mx);
    red[t] = sum; __syncthreads();
    for (int s2 = 128; s2 > 0; s2 >>= 1) {
        if (t < s2) red[t] += red[t + s2];
        __syncthreads();
    }
    if (t == 0) ((float2*)st2)[row] = make_float2(mx, 1.0f / red[0]);
}

// ---------------- softmax over contiguous rows of 256 bf16 (rou: over s at fixed n), in place
__global__ __launch_bounds__(256) void softmax_rows(ushort_t* __restrict__ R)
{
    const size_t row = (size_t)blockIdx.x * 4 + (threadIdx.x >> 6);
    const int l = threadIdx.x & 63;
    ushort4* p = (ushort4*)(R + row * 256);
    ushort4 u = p[l];
    float f0 = bf2f(u.x), f1 = bf2f(u.y), f2 = bf2f(u.z), f3 = bf2f(u.w);
    float mx = fmaxf(fmaxf(f0, f1), fmaxf(f2, f3));
#pragma unroll
    for (int m = 1; m < 64; m <<= 1) mx = fmaxf(mx, __shfl_xor(mx, m));
    f0 = __expf(f0 - mx); f1 = __expf(f1 - mx); f2 = __expf(f2 - mx); f3 = __expf(f3 - mx);
    float s = f0 + f1 + f2 + f3;
#pragma unroll
    for (int m = 1; m < 64; m <<= 1) s += __shfl_xor(s, m);
    const float inv = 1.0f / s;
    u.x = f2bf(f0 * inv); u.y = f2bf(f1 * inv); u.z = f2bf(f2 * inv); u.w = f2bf(f3 * inv);
    p[l] = u;
}

// ---------------- MFMA: P[chunk][b][k][s] = sum_{n in chunk} A[b,k,n] * w(Bm)[b,s,n]
// A: [b][64][N] bf16; Bm: [b][256][N] bf16; w() = exp-softmax weights if st2 != null
__global__ __launch_bounds__(256) void ks_mfma(
    const ushort_t* __restrict__ A, const ushort_t* __restrict__ Bm,
    const float* __restrict__ st2, float* __restrict__ P)
{
    __shared__ short sm[32768];
    const int t = threadIdx.x;
    const int l = t & 63, w = t >> 6;
    const int chunk = blockIdx.x, b = blockIdx.y;
    const int ccell = chunk * 32;

    const uint4* Av = (const uint4*)A;
    const uint4* Bv = (const uint4*)Bm;
    const float2* S2 = (const float2*)st2;
    uint4* smv = (uint4*)sm;
    const bool doexp = (st2 != nullptr);

    uint4 wreg[8], xreg[8];
    float2 sreg[8];
#pragma unroll
    for (int i = 0; i < 8; ++i) {
        int cell = i * 256 + t;
        int osub = cell >> 9, g = (cell >> 4) & 31, oi = cell & 15;
        wreg[i] = Av[(size_t)(b * 64 + osub * 16 + oi) * NC8 + ccell + g];
    }
#pragma unroll
    for (int i = 0; i < 8; ++i) {
        int cell = i * 256 + t;
        int s = cell >> 7, g8 = (cell >> 4) & 7, ni = cell & 15;
        int row = s * 16 + ni;
        xreg[i] = Bv[(size_t)(b * 256 + row) * NC8 + ccell + g8];
        if (doexp) sreg[i] = S2[b * 256 + row];
    }
#pragma unroll
    for (int i = 0; i < 8; ++i) smv[i * 256 + t] = wreg[i];
#pragma unroll
    for (int i = 0; i < 8; ++i) smv[2048 + i * 256 + t] = doexp ? expcell(xreg[i], sreg[i]) : xreg[i];
    __syncthreads();

    f32x4 zr = {0.f, 0.f, 0.f, 0.f};
    f32x4 acc[4][4];
#pragma unroll
    for (int i = 0; i < 4; ++i)
#pragma unroll
        for (int j = 0; j < 4; ++j) acc[i][j] = zr;

    const bf16x8* smW = (const bf16x8*)sm;
    const bf16x8* smX = (const bf16x8*)(sm + 16384);

    for (int st = 0; st < 4; ++st) {
        if (st < 3) {
#pragma unroll
            for (int i = 0; i < 8; ++i) {
                int cell = i * 256 + t;
                int s = cell >> 7, g8 = (cell >> 4) & 7, ni = cell & 15;
                int row = s * 16 + ni;
                xreg[i] = Bv[(size_t)(b * 256 + row) * NC8 + ccell + (st + 1) * 8 + g8];
                if (doexp) sreg[i] = S2[b * 256 + row];
            }
        }
#pragma unroll
        for (int kgl = 0; kgl < 2; ++kgl) {
            const int kg = st * 2 + kgl;
            bf16x8 Af[4], Bf[4];
#pragma unroll
            for (int os = 0; os < 4; ++os)
                Af[os] = smW[(os * 32 + kg * 4 + (l >> 4)) * 16 + (l & 15)];
#pragma unroll
            for (int j = 0; j < 4; ++j)
                Bf[j] = smX[((w * 4 + j) * 8 + kgl * 4 + (l >> 4)) * 16 + (l & 15)];
#pragma unroll
            for (int os = 0; os < 4; ++os)
#pragma unroll
                for (int j = 0; j < 4; ++j)
                    acc[os][j] = __builtin_amdgcn_mfma_f32_16x16x32_bf16(Af[os], Bf[j], acc[os][j], 0, 0, 0);
        }
        __syncthreads();
        if (st < 3) {
#pragma unroll
            for (int i = 0; i < 8; ++i) smv[2048 + i * 256 + t] = doexp ? expcell(xreg[i], sreg[i]) : xreg[i];
            __syncthreads();
        }
    }

    float* Pb = P + ((size_t)(chunk * B_ + b)) * TILE_KS;
#pragma unroll
    for (int os = 0; os < 4; ++os)
#pragma unroll
        for (int r = 0; r < 4; ++r) {
            const int k = os * 16 + (l >> 4) * 4 + r;
#pragma unroll
            for (int j = 0; j < 4; ++j)
                Pb[k * 256 + (w * 4 + j) * 16 + (l & 15)] = acc[os][j][r];
        }
}

// ---------------- MFMA: Qraw[b][n][k] = sum_s Dbf[b,k,s] * Rsm[b,n,s]; fused nrm2 atomics
__global__ __launch_bounds__(256) void qt_mfma(
    const ushort_t* __restrict__ Dbf,  // [b][64][256]
    const ushort_t* __restrict__ Rsm,  // [b][N][256]
    float* __restrict__ Qraw,          // [b][N][64]
    float* __restrict__ Nrm)           // [b][64], pre-zeroed
{
    __shared__ short sm[32768];
    const int t = threadIdx.x;
    const int l = t & 63, w = t >> 6;
    const int b = blockIdx.x / 36;
    const int n0 = (blockIdx.x % 36) * 256;

    const uint4* Av = (const uint4*)Dbf;
    const uint4* Xv = (const uint4*)Rsm;
    uint4* smv = (uint4*)sm;

    uint4 wreg[8], xreg[8];
#pragma unroll
    for (int i = 0; i < 8; ++i) {
        int cell = i * 256 + t;
        int osub = cell >> 9, g = (cell >> 4) & 31, oi = cell & 15;
        wreg[i] = Av[(size_t)(b * 64 + osub * 16 + oi) * 32 + g];
    }
#pragma unroll
    for (int i = 0; i < 8; ++i) {
        int cell = i * 256 + t;
        int s = cell >> 7, g8 = (cell >> 4) & 7, ni = cell & 15;
        xreg[i] = Xv[((size_t)b * N_ + n0 + s * 16 + ni) * 32 + g8];
    }
#pragma unroll
    for (int i = 0; i < 8; ++i) smv[i * 256 + t] = wreg[i];
#pragma unroll
    for (int i = 0; i < 8; ++i) smv[2048 + i * 256 + t] = xreg[i];
    __syncthreads();

    f32x4 zr = {0.f, 0.f, 0.f, 0.f};
    f32x4 acc[4][4];
#pragma unroll
    for (int i = 0; i < 4; ++i)
#pragma unroll
        for (int j = 0; j < 4; ++j) acc[i][j] = zr;

    const bf16x8* smW = (const bf16x8*)sm;
    const bf16x8* smX = (const bf16x8*)(sm + 16384);

    for (int st = 0; st < 4; ++st) {
        if (st < 3) {
#pragma unroll
            for (int i = 0; i < 8; ++i) {
                int cell = i * 256 + t;
                int s = cell >> 7, g8 = (cell >> 4) & 7, ni = cell & 15;
                xreg[i] = Xv[((size_t)b * N_ + n0 + s * 16 + ni) * 32 + (st + 1) * 8 + g8];
            }
        }
#pragma unroll
        for (int kgl = 0; kgl < 2; ++kgl) {
            const int kg = st * 2 + kgl;
            bf16x8 Af[4], Bf[4];
#pragma unroll
            for (int os = 0; os < 4; ++os)
                Af[os] = smW[(os * 32 + kg * 4 + (l >> 4)) * 16 + (l & 15)];
#pragma unroll
            for (int j = 0; j < 4; ++j)
                Bf[j] = smX[((w * 4 + j) * 8 + kgl * 4 + (l >> 4)) * 16 + (l & 15)];
#pragma unroll
            for (int os = 0; os < 4; ++os)
#pragma unroll
                for (int j = 0; j < 4; ++j)
                    acc[os][j] = __builtin_amdgcn_mfma_f32_16x16x32_bf16(Af[os], Bf[j], acc[os][j], 0, 0, 0);
        }
        __syncthreads();
        if (st < 3) {
#pragma unroll
            for (int i = 0; i < 8; ++i) smv[2048 + i * 256 + t] = xreg[i];
            __syncthreads();
        }
    }

    // epilogue: nrm2 partials + [n][k] transposed fp32 stores
    float* snrm = (float*)sm + 9216;
    __syncthreads();
    if (t < 64) snrm[t] = 0.f;
    __syncthreads();
#pragma unroll
    for (int os = 0; os < 4; ++os)
#pragma unroll
        for (int r = 0; r < 4; ++r) {
            float p = 0.f;
#pragma unroll
            for (int j = 0; j < 4; ++j) p = fmaf(acc[os][j][r], acc[os][j][r], p);
#pragma unroll
            for (int m = 1; m < 16; m <<= 1) p += __shfl_xor(p, m);
            if ((l & 15) == 0) atomicAdd(&snrm[os * 16 + (l >> 4) * 4 + r], p);
        }
    float* Tw = (float*)sm + w * 2304;  // per-wave [32][72]
#pragma unroll
    for (int h = 0; h < 2; ++h) {
        __syncthreads();
#pragma unroll
        for (int os = 0; os < 4; ++os)
#pragma unroll
            for (int r = 0; r < 4; ++r) {
                const int kcol = os * 16 + (l >> 4) * 4 + r;
#pragma unroll
                for (int jj = 0; jj < 2; ++jj)
                    Tw[(jj * 16 + (l & 15)) * 72 + kcol] = acc[os][h * 2 + jj][r];
            }
        __syncthreads();
#pragma unroll
        for (int i = 0; i < 8; ++i) {
            const int lrow = i * 4 + (l >> 4);
            f32x4 v = *(const f32x4*)&Tw[lrow * 72 + (l & 15) * 4];
            *(f32x4*)&Qraw[((size_t)b * N_ + n0 + w * 64 + h * 32 + lrow) * 64 + (l & 15) * 4] = v;
        }
    }
    __syncthreads();
    if (t < 64) atomicAdd(&Nrm[b * 64 + t], snrm[t]);
}

// ---------------- partial-sum reductions over NCHUNK
__global__ __launch_bounds__(256) void chunk_reduce_bf(
    const float* __restrict__ P, ushort_t* __restrict__ outb)
{
    const int i = blockIdx.x * 256 + threadIdx.x;
    float s = 0.f;
#pragma unroll
    for (int c = 0; c < NCHUNK; ++c) s += P[(size_t)c * (B_ * TILE_KS) + i];
    outb[i] = f2bf(s);
}
__global__ __launch_bounds__(256) void chunk_reduce_f(
    const float* __restrict__ P, float* __restrict__ outf)
{
    const int i = blockIdx.x * 256 + threadIdx.x;
    float s = 0.f;
#pragma unroll
    for (int c = 0; c < NCHUNK; ++c) s += P[(size_t)c * (B_ * TILE_KS) + i];
    outf[i] = s;
}

// ---------------- Q = softmax_k(Qraw * invn); write Qout[b][n][k] fp32 + Qbf[b][k][n] bf16
__global__ __launch_bounds__(256) void q_final(
    const float* __restrict__ Qraw, const float* __restrict__ Nrm,
    float* __restrict__ Qout, ushort_t* __restrict__ Qbf)
{
    __shared__ ushort_t Tq[64 * 256];
    __shared__ float invn[64];
    const int b = blockIdx.y;
    const int n0 = blockIdx.x * 256;
    const int t = threadIdx.x;
    const int l = t & 63, w = t >> 6;
    if (t < 64) invn[t] = 1.0f / fmaxf(sqrtf(Nrm[b * 64 + t]), 1e-12f);
    __syncthreads();
    const size_t base = ((size_t)b * N_ + n0 + t) * 64;
    float q[64];
#pragma unroll
    for (int kk = 0; kk < 16; ++kk) {
        f32x4 v = *(const f32x4*)&Qraw[base + kk * 4];
        q[kk * 4 + 0] = v[0]; q[kk * 4 + 1] = v[1]; q[kk * 4 + 2] = v[2]; q[kk * 4 + 3] = v[3];
    }
    float mx = -INFINITY;
#pragma unroll
    for (int k = 0; k < 64; ++k) { q[k] *= invn[k]; mx = fmaxf(mx, q[k]); }
    float sum = 0.f;
#pragma unroll
    for (int k = 0; k < 64; ++k) { q[k] = __expf(q[k] - mx); sum += q[k]; }
    const float inv = 1.0f / sum;
#pragma unroll
    for (int kk = 0; kk < 16; ++kk) {
        f32x4 v = {q[kk * 4] * inv, q[kk * 4 + 1] * inv, q[kk * 4 + 2] * inv, q[kk * 4 + 3] * inv};
        *(f32x4*)&Qout[base + kk * 4] = v;
        q[kk * 4] = v[0]; q[kk * 4 + 1] = v[1]; q[kk * 4 + 2] = v[2]; q[kk * 4 + 3] = v[3];
    }
#pragma unroll
    for (int k = 0; k < 64; ++k) Tq[k * 256 + t] = f2bf(q[k]);
    __syncthreads();
#pragma unroll
    for (int kk = 0; kk < 16; ++kk) {
        const int k = kk * 4 + w;
        ushort4 v = *(const ushort4*)&Tq[k * 256 + l * 4];
        *(ushort4*)&Qbf[((size_t)b * 64 + k) * N_ + n0 + l * 4] = v;
    }
}

// ---------------- Z[b,s,k] = ZnT[b,k,s] / ||ZnT[b,:,k]... norm over s|| (qsum cancels in l2norm)
__global__ __launch_bounds__(256) void z_final(
    const float* __restrict__ ZnT, float* __restrict__ Z)
{
    __shared__ float red[256];
    __shared__ float invn[64];
    const int b = blockIdx.x;
    const int t = threadIdx.x;
    const float* Zb = ZnT + (size_t)b * TILE_KS;
    {
        const int k = t >> 2, qq = t & 3;
        float ss = 0.f;
        for (int j = 0; j < 64; ++j) {
            float v = Zb[k * 256 + qq * 64 + j];
            ss = fmaf(v, v, ss);
        }
        red[t] = ss;
    }
    __syncthreads();
    if ((t & 3) == 0) {
        float tot = red[t] + red[t + 1] + red[t + 2] + red[t + 3];
        invn[t >> 2] = 1.0f / fmaxf(sqrtf(tot), 1e-12f);
    }
    __syncthreads();
    {
        const int k = t & 63, w = t >> 6;
        const float sc = invn[k];
        for (int j = 0; j < 64; ++j) {
            int s = w * 64 + j;
            Z[((size_t)b * 256 + s) * 64 + k] = Zb[k * 256 + s] * sc;
        }
    }
}

extern "C" void kernel_launch(void* const* d_in, const int* in_sizes, int n_in,
                              void* d_out, int out_size, void* d_ws, size_t ws_size,
                              hipStream_t stream)
{
    const float* X       = (const float*)d_in[0];
    const float* phi_w   = (const float*)d_in[1];
    const float* phi_g   = (const float*)d_in[2];
    const float* phi_b   = (const float*)d_in[3];
    const float* phi_m   = (const float*)d_in[4];
    const float* phi_v   = (const float*)d_in[5];
    const float* theta_w = (const float*)d_in[6];
    const float* theta_g = (const float*)d_in[7];
    const float* theta_b = (const float*)d_in[8];
    const float* theta_m = (const float*)d_in[9];
    const float* theta_v = (const float*)d_in[10];
    const float* rou_w   = (const float*)d_in[11];
    const float* rou_g   = (const float*)d_in[12];
    const float* rou_b   = (const float*)d_in[13];
    const float* rou_m   = (const float*)d_in[14];
    const float* rou_v   = (const float*)d_in[15];
    const float* val_w   = (const float*)d_in[16];
    const float* val_g   = (const float*)d_in[17];
    const float* val_b   = (const float*)d_in[18];
    const float* val_m   = (const float*)d_in[19];
    const float* val_v   = (const float*)d_in[20];

    float* ws = (float*)d_ws;
    size_t off = 0;
    ushort_t* Xb  = (ushort_t*)(ws + off); off += (size_t)B_ * N_ * C_ / 2;
    ushort_t* Wb  = (ushort_t*)(ws + off); off += 832 * C_ / 2;
    float* be     = ws + off; off += 832;
    float* st2    = ws + off; off += 2 * B_ * 256;
    ushort_t* Pbf = (ushort_t*)(ws + off); off += (size_t)B_ * 64 * N_ / 2;
    ushort_t* Tbf = (ushort_t*)(ws + off); off += (size_t)B_ * 256 * N_ / 2;
    ushort_t* Vbf = (ushort_t*)(ws + off); off += (size_t)B_ * 256 * N_ / 2;
    ushort_t* Rt  = (ushort_t*)(ws + off); off += (size_t)B_ * N_ * 256 / 2;
    ushort_t* Qbf = (ushort_t*)(ws + off); off += (size_t)B_ * 64 * N_ / 2;
    ushort_t* Dbf = (ushort_t*)(ws + off); off += (size_t)B_ * 64 * 256 / 2;
    float* part   = ws + off; off += (size_t)NCHUNK * B_ * TILE_KS;
    float* Qraw   = ws + off; off += (size_t)B_ * N_ * 64;
    float* ZnT    = ws + off; off += (size_t)B_ * TILE_KS;
    float* Nrm    = ws + off; off += B_ * 64;

    float* Zout = (float*)d_out;                  // B*S*K
    float* Qout = Zout + (size_t)B_ * S_ * K_;    // B*N*K

    hipMemsetAsync(Nrm, 0, B_ * 64 * sizeof(float), stream);

    prep_w<<<832, 256, 0, stream>>>(phi_w, phi_g, phi_b, phi_m, phi_v,
                                    theta_w, theta_g, theta_b, theta_m, theta_v,
                                    rou_w, rou_g, rou_b, rou_m, rou_v,
                                    val_w, val_g, val_b, val_m, val_v, Wb, be);
    xpose<<<dim3(N_ / 64, C_ / 64, B_), 256, 0, stream>>>(X, Xb);

    proj_mfma_all<<<dim3(36 * B_, 13), 256, 0, stream>>>(Wb, be, Xb, Pbf, Tbf, Vbf, Rt);

    rowstat_n<<<B_ * 256, 256, 0, stream>>>(Tbf, st2);
    softmax_rows<<<B_ * N_ / 4, 256, 0, stream>>>(Rt);

    ks_mfma<<<dim3(NCHUNK, B_), 256, 0, stream>>>(Pbf, Tbf, st2, part);
    chunk_reduce_bf<<<B_ * TILE_KS / 256, 256, 0, stream>>>(part, Dbf);

    qt_mfma<<<36 * B_, 256, 0, stream>>>(Dbf, Rt, Qraw, Nrm);
    q_final<<<dim3(36, B_), 256, 0, stream>>>(Qraw, Nrm, Qout, Qbf);

    ks_mfma<<<dim3(NCHUNK, B_), 256, 0, stream>>>(Qbf, Vbf, (const float*)nullptr, part);
    chunk_reduce_f<<<B_ * TILE_KS / 256, 256, 0, stream>>>(part, ZnT);
    z_final<<<B_, 256, 0, stream>>>(ZnT, Zout);
}

// Round 8
// 338.005 us; speedup vs baseline: 2.2753x; 1.0456x over previous
//
#include <hip/hip_runtime.h>
#include <math.h>

#define B_ 8
#define C_ 256
#define N_ 9216
#define S_ 256
#define K_ 64
#define NCHUNK 36            // 9216 / 256
#define TILE_KS (K_ * S_)    // 16384
#define NC8 (N_ / 8)         // 1152 16B-cells per [*][N] bf16 row

typedef unsigned short ushort_t;
typedef __attribute__((ext_vector_type(8))) short bf16x8;
typedef __attribute__((ext_vector_type(4))) float f32x4;

static __device__ inline ushort_t f2bf(float x) {
    unsigned int u = __float_as_uint(x);
    unsigned int r = (u + 0x7fffu + ((u >> 16) & 1u)) >> 16;
    return (ushort_t)r;
}
static __device__ inline float bf2f(ushort_t u) {
    return __uint_as_float(((unsigned int)u) << 16);
}

// exp-weight one 8-bf16 cell (row-constant max/invsum in s)
static __device__ inline uint4 expcell(uint4 u, float2 s) {
    uint4 r;
    unsigned int* up = (unsigned int*)&u;
    unsigned int* rp = (unsigned int*)&r;
#pragma unroll
    for (int q = 0; q < 4; ++q) {
        unsigned int x = up[q];
        float lo = __uint_as_float((x & 0xffffu) << 16);
        float hi = __uint_as_float(x & 0xffff0000u);
        float el = __expf(lo - s.x) * s.y;
        float eh = __expf(hi - s.x) * s.y;
        rp[q] = (unsigned int)f2bf(el) | ((unsigned int)f2bf(eh) << 16);
    }
    return r;
}

// ---------------- fold BN scale into W, convert to bf16; be[o] = b - m*s
__global__ __launch_bounds__(256) void prep_w(
    const float* __restrict__ phi_w, const float* __restrict__ phi_g, const float* __restrict__ phi_b,
    const float* __restrict__ phi_m, const float* __restrict__ phi_v,
    const float* __restrict__ th_w, const float* __restrict__ th_g, const float* __restrict__ th_b,
    const float* __restrict__ th_m, const float* __restrict__ th_v,
    const float* __restrict__ ro_w, const float* __restrict__ ro_g, const float* __restrict__ ro_b,
    const float* __restrict__ ro_m, const float* __restrict__ ro_v,
    const float* __restrict__ va_w, const float* __restrict__ va_g, const float* __restrict__ va_b,
    const float* __restrict__ va_m, const float* __restrict__ va_v,
    ushort_t* __restrict__ Wb, float* __restrict__ be)
{
    const int o = blockIdx.x;  // 0..831
    const int t = threadIdx.x; // = c
    const float *src, *g, *bb, *mm, *vv; int orel;
    if (o < 64)       { src = phi_w; g = phi_g; bb = phi_b; mm = phi_m; vv = phi_v; orel = o; }
    else if (o < 320) { src = th_w;  g = th_g;  bb = th_b;  mm = th_m;  vv = th_v;  orel = o - 64; }
    else if (o < 576) { src = ro_w;  g = ro_g;  bb = ro_b;  mm = ro_m;  vv = ro_v;  orel = o - 320; }
    else              { src = va_w;  g = va_g;  bb = va_b;  mm = va_m;  vv = va_v;  orel = o - 576; }
    const float s = g[orel] / sqrtf(vv[orel] + 1e-5f);
    Wb[o * C_ + t] = f2bf(src[orel * C_ + t] * s);
    if (t == 0) be[o] = bb[orel] - mm[orel] * s;
}

// ---------------- X[b][c][n] fp32 -> Xb[b][n][c] bf16
__global__ __launch_bounds__(256) void xpose(
    const float* __restrict__ X, ushort_t* __restrict__ Xb)
{
    __shared__ float T[64][65];
    const int b = blockIdx.z, c0 = blockIdx.y * 64, n0 = blockIdx.x * 64;
    const int t = threadIdx.x;
#pragma unroll
    for (int p = 0; p < 4; ++p) {
        int c = p * 16 + (t >> 4), nn = (t & 15) * 4;
        float4 v = *(const float4*)&X[((size_t)b * C_ + c0 + c) * N_ + n0 + nn];
        T[c][nn] = v.x; T[c][nn + 1] = v.y; T[c][nn + 2] = v.z; T[c][nn + 3] = v.w;
    }
    __syncthreads();
#pragma unroll
    for (int p = 0; p < 4; ++p) {
        int nn = p * 16 + (t >> 4), cl = (t & 15) * 4;
        ushort4 u;
        u.x = f2bf(T[cl][nn]); u.y = f2bf(T[cl + 1][nn]);
        u.z = f2bf(T[cl + 2][nn]); u.w = f2bf(T[cl + 3][nn]);
        *(ushort4*)&Xb[((size_t)b * N_ + n0 + nn) * C_ + c0 + cl] = u;
    }
}

// ---------------- fused bf16-MFMA projection, ALL 13 o-tiles, bf16 outputs.
// Flat grid, XCD-bijective decode with o-tile FASTEST: the 13 o-tiles sharing an
// X-tile run back-to-back on one XCD -> X fetched from HBM once (R6: 13x sweep, 298MB).
// LDS is 64KB: W stage 32KB (64o x 256c) + X stage 32KB (256n x 64c). (R7 bug: 48KB
// declared with same staging pattern -> OOB LDS writes. Keep 64KB.)
__global__ __launch_bounds__(256) void proj_mfma_all(
    const ushort_t* __restrict__ Wb, const float* __restrict__ be,
    const ushort_t* __restrict__ Xb,
    ushort_t* __restrict__ Pbf, ushort_t* __restrict__ Tbf,
    ushort_t* __restrict__ Vbf, ushort_t* __restrict__ Rt)
{
    __shared__ short sm[32768];  // 64 KB: W cells [0,2048), X cells [2048,4096) (16B cells)
    const int t = threadIdx.x;
    const int l = t & 63, w = t >> 6;
    const int idx = blockIdx.x;          // 0..3743
    const int xcd = idx & 7, pos = idx >> 3;
    const int vid = xcd * 468 + pos;     // 468 = 36*13 blocks per XCD chunk
    const int ot  = vid % 13;
    const int r   = vid / 13;            // 0..287
    const int b   = r / 36;
    const int n0  = (r % 36) * 256;
    const int o0  = ot * 64;

    const uint4* Wv = (const uint4*)Wb;
    const uint4* Xv = (const uint4*)Xb;
    uint4* smv = (uint4*)sm;

    uint4 wreg[8], xreg[8];
#pragma unroll
    for (int i = 0; i < 8; ++i) {
        int cell = i * 256 + t;
        int osub = cell >> 9, g = (cell >> 4) & 31, oi = cell & 15;
        wreg[i] = Wv[(size_t)(o0 + osub * 16 + oi) * 32 + g];
    }
#pragma unroll
    for (int i = 0; i < 8; ++i) {
        int cell = i * 256 + t;
        int s = cell >> 7, g8 = (cell >> 4) & 7, ni = cell & 15;
        xreg[i] = Xv[(size_t)(b * N_ + n0 + s * 16 + ni) * 32 + g8];
    }
#pragma unroll
    for (int i = 0; i < 8; ++i) smv[i * 256 + t] = wreg[i];
#pragma unroll
    for (int i = 0; i < 8; ++i) smv[2048 + i * 256 + t] = xreg[i];
    __syncthreads();

    f32x4 zr = {0.f, 0.f, 0.f, 0.f};
    f32x4 acc[4][4];
#pragma unroll
    for (int i = 0; i < 4; ++i)
#pragma unroll
        for (int j = 0; j < 4; ++j) acc[i][j] = zr;

    const bf16x8* smW = (const bf16x8*)sm;
    const bf16x8* smX = (const bf16x8*)(sm + 16384);

    for (int st = 0; st < 4; ++st) {
        if (st < 3) {  // early-issue next stage's global loads (hide under MFMA)
#pragma unroll
            for (int i = 0; i < 8; ++i) {
                int cell = i * 256 + t;
                int s = cell >> 7, g8 = (cell >> 4) & 7, ni = cell & 15;
                xreg[i] = Xv[(size_t)(b * N_ + n0 + s * 16 + ni) * 32 + (st + 1) * 8 + g8];
            }
        }
#pragma unroll
        for (int kgl = 0; kgl < 2; ++kgl) {
            const int kg = st * 2 + kgl;
            bf16x8 A[4], Bf[4];
#pragma unroll
            for (int os = 0; os < 4; ++os)
                A[os] = smW[(os * 32 + kg * 4 + (l >> 4)) * 16 + (l & 15)];
#pragma unroll
            for (int j = 0; j < 4; ++j)
                Bf[j] = smX[((w * 4 + j) * 8 + kgl * 4 + (l >> 4)) * 16 + (l & 15)];
#pragma unroll
            for (int os = 0; os < 4; ++os)
#pragma unroll
                for (int j = 0; j < 4; ++j)
                    acc[os][j] = __builtin_amdgcn_mfma_f32_16x16x32_bf16(A[os], Bf[j], acc[os][j], 0, 0, 0);
        }
        __syncthreads();
        if (st < 3) {
#pragma unroll
            for (int i = 0; i < 8; ++i) smv[2048 + i * 256 + t] = xreg[i];
            __syncthreads();
        }
    }

    // epilogue (block-uniform branch on o0)
    if (o0 >= 320 && o0 < 576) {
        // rou -> Rt[b][n][256s] (transposed), per-wave [64n][72pad] bf16 tile
        const int od = o0 - 320;
        ushort_t* Tt = (ushort_t*)sm + w * (64 * 72);
        __syncthreads();
#pragma unroll
        for (int os = 0; os < 4; ++os)
#pragma unroll
            for (int r2 = 0; r2 < 4; ++r2) {
                const int scol = os * 16 + (l >> 4) * 4 + r2;
                const float bias = be[o0 + scol];
#pragma unroll
                for (int j = 0; j < 4; ++j)
                    Tt[(j * 16 + (l & 15)) * 72 + scol] = f2bf(fmaxf(acc[os][j][r2] + bias, 0.f));
            }
        __syncthreads();
#pragma unroll
        for (int p = 0; p < 8; ++p) {
            const int row = p * 8 + (l >> 3);
            uint4 v = *(const uint4*)&Tt[row * 72 + (l & 7) * 8];
            *(uint4*)&Rt[((size_t)b * N_ + n0 + w * 64 + row) * 256 + od + (l & 7) * 8] = v;
        }
    } else {
        ushort_t* dst; int od, osz;
        if (o0 < 64)       { dst = Pbf; od = o0;       osz = 64;  }
        else if (o0 < 320) { dst = Tbf; od = o0 - 64;  osz = 256; }
        else               { dst = Vbf; od = o0 - 576; osz = 256; }
        ushort_t* Tw = (ushort_t*)sm + w * (32 * 68);
#pragma unroll
        for (int half = 0; half < 2; ++half) {
            __syncthreads();
#pragma unroll
            for (int osl = 0; osl < 2; ++osl) {
                const int os = half * 2 + osl;
#pragma unroll
                for (int r2 = 0; r2 < 4; ++r2) {
                    const int lrow = osl * 16 + (l >> 4) * 4 + r2;
                    const int orow = half * 32 + lrow;
                    const float bias = be[o0 + orow];
#pragma unroll
                    for (int j = 0; j < 4; ++j)
                        Tw[lrow * 68 + j * 16 + (l & 15)] = f2bf(fmaxf(acc[os][j][r2] + bias, 0.f));
                }
            }
            __syncthreads();
#pragma unroll
            for (int i = 0; i < 8; ++i) {
                const int lrow = i * 4 + (l >> 4);
                ushort4 v = *(const ushort4*)&Tw[lrow * 68 + (l & 15) * 4];
                *(ushort4*)&dst[((size_t)(b * osz + od + half * 32 + lrow)) * N_ + n0 + w * 64 + (l & 15) * 4] = v;
            }
        }
    }
}

// ---------------- theta row stats: st2[row] = (max, 1/sum(exp(x-max))) over N
__global__ __launch_bounds__(256) void rowstat_n(
    const ushort_t* __restrict__ T, float* __restrict__ st2)
{
    const int row = blockIdx.x;  // b*256 + s
    const ushort4* p = (const ushort4*)(T + (size_t)row * N_);
    const int t = threadIdx.x;
    float v[36];
    float mx = -INFINITY;
#pragma unroll
    for (int i = 0; i < 9; ++i) {
        ushort4 u = p[t + i * 256];
        v[i * 4 + 0] = bf2f(u.x); v[i * 4 + 1] = bf2f(u.y);
        v[i * 4 + 2] = bf2f(u.z); v[i * 4 + 3] = bf2f(u.w);
        mx = fmaxf(mx, fmaxf(fmaxf(v[i * 4], v[i * 4 + 1]), fmaxf(v[i * 4 + 2], v[i * 4 + 3])));
    }
    __shared__ float red[256];
    red[t] = mx; __syncthreads();
    for (int s2 = 128; s2 > 0; s2 >>= 1) {
        if (t < s2) red[t] = fmaxf(red[t], red[t + s2]);
        __syncthreads();
    }
    mx = red[0]; __syncthreads();
    float sum = 0.f;
#pragma unroll
    for (int i = 0; i < 36; ++i) sum += __expf(v[i] - mx);
    red[t] = sum; __syncthreads();
    for (int s2 = 128; s2 > 0; s2 >>= 1) {
        if (t < s2) red[t] += red[t + s2];
        __syncthreads();
    }
    if (t == 0) ((float2*)st2)[row] = make_float2(mx, 1.0f / red[0]);
}

// ---------------- softmax over contiguous rows of 256 bf16 (rou: over s at fixed n), in place
__global__ __launch_bounds__(256) void softmax_rows(ushort_t* __restrict__ R)
{
    const size_t row = (size_t)blockIdx.x * 4 + (threadIdx.x >> 6);
    const int l = threadIdx.x & 63;
    ushort4* p = (ushort4*)(R + row * 256);
    ushort4 u = p[l];
    float f0 = bf2f(u.x), f1 = bf2f(u.y), f2 = bf2f(u.z), f3 = bf2f(u.w);
    float mx = fmaxf(fmaxf(f0, f1), fmaxf(f2, f3));
#pragma unroll
    for (int m = 1; m < 64; m <<= 1) mx = fmaxf(mx, __shfl_xor(mx, m));
    f0 = __expf(f0 - mx); f1 = __expf(f1 - mx); f2 = __expf(f2 - mx); f3 = __expf(f3 - mx);
    float s = f0 + f1 + f2 + f3;
#pragma unroll
    for (int m = 1; m < 64; m <<= 1) s += __shfl_xor(s, m);
    const float inv = 1.0f / s;
    u.x = f2bf(f0 * inv); u.y = f2bf(f1 * inv); u.z = f2bf(f2 * inv); u.w = f2bf(f3 * inv);
    p[l] = u;
}

// ---------------- MFMA: P[chunk][b][k][s] = sum_{n in chunk} A[b,k,n] * w(Bm)[b,s,n]
__global__ __launch_bounds__(256) void ks_mfma(
    const ushort_t* __restrict__ A, const ushort_t* __restrict__ Bm,
    const float* __restrict__ st2, float* __restrict__ P)
{
    __shared__ short sm[32768];
    const int t = threadIdx.x;
    const int l = t & 63, w = t >> 6;
    const int chunk = blockIdx.x, b = blockIdx.y;
    const int ccell = chunk * 32;

    const uint4* Av = (const uint4*)A;
    const uint4* Bv = (const uint4*)Bm;
    const float2* S2 = (const float2*)st2;
    uint4* smv = (uint4*)sm;
    const bool doexp = (st2 != nullptr);

    uint4 wreg[8], xreg[8];
    float2 sreg[8];
#pragma unroll
    for (int i = 0; i < 8; ++i) {
        int cell = i * 256 + t;
        int osub = cell >> 9, g = (cell >> 4) & 31, oi = cell & 15;
        wreg[i] = Av[(size_t)(b * 64 + osub * 16 + oi) * NC8 + ccell + g];
    }
#pragma unroll
    for (int i = 0; i < 8; ++i) {
        int cell = i * 256 + t;
        int s = cell >> 7, g8 = (cell >> 4) & 7, ni = cell & 15;
        int row = s * 16 + ni;
        xreg[i] = Bv[(size_t)(b * 256 + row) * NC8 + ccell + g8];
        if (doexp) sreg[i] = S2[b * 256 + row];
    }
#pragma unroll
    for (int i = 0; i < 8; ++i) smv[i * 256 + t] = wreg[i];
#pragma unroll
    for (int i = 0; i < 8; ++i) smv[2048 + i * 256 + t] = doexp ? expcell(xreg[i], sreg[i]) : xreg[i];
    __syncthreads();

    f32x4 zr = {0.f, 0.f, 0.f, 0.f};
    f32x4 acc[4][4];
#pragma unroll
    for (int i = 0; i < 4; ++i)
#pragma unroll
        for (int j = 0; j < 4; ++j) acc[i][j] = zr;

    const bf16x8* smW = (const bf16x8*)sm;
    const bf16x8* smX = (const bf16x8*)(sm + 16384);

    for (int st = 0; st < 4; ++st) {
        if (st < 3) {
#pragma unroll
            for (int i = 0; i < 8; ++i) {
                int cell = i * 256 + t;
                int s = cell >> 7, g8 = (cell >> 4) & 7, ni = cell & 15;
                int row = s * 16 + ni;
                xreg[i] = Bv[(size_t)(b * 256 + row) * NC8 + ccell + (st + 1) * 8 + g8];
                if (doexp) sreg[i] = S2[b * 256 + row];
            }
        }
#pragma unroll
        for (int kgl = 0; kgl < 2; ++kgl) {
            const int kg = st * 2 + kgl;
            bf16x8 Af[4], Bf[4];
#pragma unroll
            for (int os = 0; os < 4; ++os)
                Af[os] = smW[(os * 32 + kg * 4 + (l >> 4)) * 16 + (l & 15)];
#pragma unroll
            for (int j = 0; j < 4; ++j)
                Bf[j] = smX[((w * 4 + j) * 8 + kgl * 4 + (l >> 4)) * 16 + (l & 15)];
#pragma unroll
            for (int os = 0; os < 4; ++os)
#pragma unroll
                for (int j = 0; j < 4; ++j)
                    acc[os][j] = __builtin_amdgcn_mfma_f32_16x16x32_bf16(Af[os], Bf[j], acc[os][j], 0, 0, 0);
        }
        __syncthreads();
        if (st < 3) {
#pragma unroll
            for (int i = 0; i < 8; ++i) smv[2048 + i * 256 + t] = doexp ? expcell(xreg[i], sreg[i]) : xreg[i];
            __syncthreads();
        }
    }

    float* Pb = P + ((size_t)(chunk * B_ + b)) * TILE_KS;
#pragma unroll
    for (int os = 0; os < 4; ++os)
#pragma unroll
        for (int r = 0; r < 4; ++r) {
            const int k = os * 16 + (l >> 4) * 4 + r;
#pragma unroll
            for (int j = 0; j < 4; ++j)
                Pb[k * 256 + (w * 4 + j) * 16 + (l & 15)] = acc[os][j][r];
        }
}

// ---------------- MFMA: Qraw[b][n][k] = sum_s Dbf[b,k,s] * Rsm[b,n,s]; fused nrm2 atomics
__global__ __launch_bounds__(256) void qt_mfma(
    const ushort_t* __restrict__ Dbf,  // [b][64][256]
    const ushort_t* __restrict__ Rsm,  // [b][N][256]
    float* __restrict__ Qraw,          // [b][N][64]
    float* __restrict__ Nrm)           // [b][64], pre-zeroed
{
    __shared__ short sm[32768];
    const int t = threadIdx.x;
    const int l = t & 63, w = t >> 6;
    const int b = blockIdx.x / 36;
    const int n0 = (blockIdx.x % 36) * 256;

    const uint4* Av = (const uint4*)Dbf;
    const uint4* Xv = (const uint4*)Rsm;
    uint4* smv = (uint4*)sm;

    uint4 wreg[8], xreg[8];
#pragma unroll
    for (int i = 0; i < 8; ++i) {
        int cell = i * 256 + t;
        int osub = cell >> 9, g = (cell >> 4) & 31, oi = cell & 15;
        wreg[i] = Av[(size_t)(b * 64 + osub * 16 + oi) * 32 + g];
    }
#pragma unroll
    for (int i = 0; i < 8; ++i) {
        int cell = i * 256 + t;
        int s = cell >> 7, g8 = (cell >> 4) & 7, ni = cell & 15;
        xreg[i] = Xv[((size_t)b * N_ + n0 + s * 16 + ni) * 32 + g8];
    }
#pragma unroll
    for (int i = 0; i < 8; ++i) smv[i * 256 + t] = wreg[i];
#pragma unroll
    for (int i = 0; i < 8; ++i) smv[2048 + i * 256 + t] = xreg[i];
    __syncthreads();

    f32x4 zr = {0.f, 0.f, 0.f, 0.f};
    f32x4 acc[4][4];
#pragma unroll
    for (int i = 0; i < 4; ++i)
#pragma unroll
        for (int j = 0; j < 4; ++j) acc[i][j] = zr;

    const bf16x8* smW = (const bf16x8*)sm;
    const bf16x8* smX = (const bf16x8*)(sm + 16384);

    for (int st = 0; st < 4; ++st) {
        if (st < 3) {
#pragma unroll
            for (int i = 0; i < 8; ++i) {
                int cell = i * 256 + t;
                int s = cell >> 7, g8 = (cell >> 4) & 7, ni = cell & 15;
                xreg[i] = Xv[((size_t)b * N_ + n0 + s * 16 + ni) * 32 + (st + 1) * 8 + g8];
            }
        }
#pragma unroll
        for (int kgl = 0; kgl < 2; ++kgl) {
            const int kg = st * 2 + kgl;
            bf16x8 Af[4], Bf[4];
#pragma unroll
            for (int os = 0; os < 4; ++os)
                Af[os] = smW[(os * 32 + kg * 4 + (l >> 4)) * 16 + (l & 15)];
#pragma unroll
            for (int j = 0; j < 4; ++j)
                Bf[j] = smX[((w * 4 + j) * 8 + kgl * 4 + (l >> 4)) * 16 + (l & 15)];
#pragma unroll
            for (int os = 0; os < 4; ++os)
#pragma unroll
                for (int j = 0; j < 4; ++j)
                    acc[os][j] = __builtin_amdgcn_mfma_f32_16x16x32_bf16(Af[os], Bf[j], acc[os][j], 0, 0, 0);
        }
        __syncthreads();
        if (st < 3) {
#pragma unroll
            for (int i = 0; i < 8; ++i) smv[2048 + i * 256 + t] = xreg[i];
            __syncthreads();
        }
    }

    // epilogue: nrm2 partials + [n][k] transposed fp32 stores
    float* snrm = (float*)sm + 9216;
    __syncthreads();
    if (t < 64) snrm[t] = 0.f;
    __syncthreads();
#pragma unroll
    for (int os = 0; os < 4; ++os)
#pragma unroll
        for (int r = 0; r < 4; ++r) {
            float p = 0.f;
#pragma unroll
            for (int j = 0; j < 4; ++j) p = fmaf(acc[os][j][r], acc[os][j][r], p);
#pragma unroll
            for (int m = 1; m < 16; m <<= 1) p += __shfl_xor(p, m);
            if ((l & 15) == 0) atomicAdd(&snrm[os * 16 + (l >> 4) * 4 + r], p);
        }
    float* Tw = (float*)sm + w * 2304;  // per-wave [32][72]
#pragma unroll
    for (int h = 0; h < 2; ++h) {
        __syncthreads();
#pragma unroll
        for (int os = 0; os < 4; ++os)
#pragma unroll
            for (int r = 0; r < 4; ++r) {
                const int kcol = os * 16 + (l >> 4) * 4 + r;
#pragma unroll
                for (int jj = 0; jj < 2; ++jj)
                    Tw[(jj * 16 + (l & 15)) * 72 + kcol] = acc[os][h * 2 + jj][r];
            }
        __syncthreads();
#pragma unroll
        for (int i = 0; i < 8; ++i) {
            const int lrow = i * 4 + (l >> 4);
            f32x4 v = *(const f32x4*)&Tw[lrow * 72 + (l & 15) * 4];
            *(f32x4*)&Qraw[((size_t)b * N_ + n0 + w * 64 + h * 32 + lrow) * 64 + (l & 15) * 4] = v;
        }
    }
    __syncthreads();
    if (t < 64) atomicAdd(&Nrm[b * 64 + t], snrm[t]);
}

// ---------------- partial-sum reductions over NCHUNK
__global__ __launch_bounds__(256) void chunk_reduce_bf(
    const float* __restrict__ P, ushort_t* __restrict__ outb)
{
    const int i = blockIdx.x * 256 + threadIdx.x;
    float s = 0.f;
#pragma unroll
    for (int c = 0; c < NCHUNK; ++c) s += P[(size_t)c * (B_ * TILE_KS) + i];
    outb[i] = f2bf(s);
}
__global__ __launch_bounds__(256) void chunk_reduce_f(
    const float* __restrict__ P, float* __restrict__ outf)
{
    const int i = blockIdx.x * 256 + threadIdx.x;
    float s = 0.f;
#pragma unroll
    for (int c = 0; c < NCHUNK; ++c) s += P[(size_t)c * (B_ * TILE_KS) + i];
    outf[i] = s;
}

// ---------------- Q = softmax_k(Qraw * invn); write Qout[b][n][k] fp32 + Qbf[b][k][n] bf16
__global__ __launch_bounds__(256) void q_final(
    const float* __restrict__ Qraw, const float* __restrict__ Nrm,
    float* __restrict__ Qout, ushort_t* __restrict__ Qbf)
{
    __shared__ ushort_t Tq[64 * 256];
    __shared__ float invn[64];
    const int b = blockIdx.y;
    const int n0 = blockIdx.x * 256;
    const int t = threadIdx.x;
    const int l = t & 63, w = t >> 6;
    if (t < 64) invn[t] = 1.0f / fmaxf(sqrtf(Nrm[b * 64 + t]), 1e-12f);
    __syncthreads();
    const size_t base = ((size_t)b * N_ + n0 + t) * 64;
    float q[64];
#pragma unroll
    for (int kk = 0; kk < 16; ++kk) {
        f32x4 v = *(const f32x4*)&Qraw[base + kk * 4];
        q[kk * 4 + 0] = v[0]; q[kk * 4 + 1] = v[1]; q[kk * 4 + 2] = v[2]; q[kk * 4 + 3] = v[3];
    }
    float mx = -INFINITY;
#pragma unroll
    for (int k = 0; k < 64; ++k) { q[k] *= invn[k]; mx = fmaxf(mx, q[k]); }
    float sum = 0.f;
#pragma unroll
    for (int k = 0; k < 64; ++k) { q[k] = __expf(q[k] - mx); sum += q[k]; }
    const float inv = 1.0f / sum;
#pragma unroll
    for (int kk = 0; kk < 16; ++kk) {
        f32x4 v = {q[kk * 4] * inv, q[kk * 4 + 1] * inv, q[kk * 4 + 2] * inv, q[kk * 4 + 3] * inv};
        *(f32x4*)&Qout[base + kk * 4] = v;
        q[kk * 4] = v[0]; q[kk * 4 + 1] = v[1]; q[kk * 4 + 2] = v[2]; q[kk * 4 + 3] = v[3];
    }
#pragma unroll
    for (int k = 0; k < 64; ++k) Tq[k * 256 + t] = f2bf(q[k]);
    __syncthreads();
#pragma unroll
    for (int kk = 0; kk < 16; ++kk) {
        const int k = kk * 4 + w;
        ushort4 v = *(const ushort4*)&Tq[k * 256 + l * 4];
        *(ushort4*)&Qbf[((size_t)b * 64 + k) * N_ + n0 + l * 4] = v;
    }
}

// ---------------- Z[b,s,k] = ZnT[b,k,s] / l2norm over s (qsum cancels in l2norm)
__global__ __launch_bounds__(256) void z_final(
    const float* __restrict__ ZnT, float* __restrict__ Z)
{
    __shared__ float red[256];
    __shared__ float invn[64];
    const int b = blockIdx.x;
    const int t = threadIdx.x;
    const float* Zb = ZnT + (size_t)b * TILE_KS;
    {
        const int k = t >> 2, qq = t & 3;
        float ss = 0.f;
        for (int j = 0; j < 64; ++j) {
            float v = Zb[k * 256 + qq * 64 + j];
            ss = fmaf(v, v, ss);
        }
        red[t] = ss;
    }
    __syncthreads();
    if ((t & 3) == 0) {
        float tot = red[t] + red[t + 1] + red[t + 2] + red[t + 3];
        invn[t >> 2] = 1.0f / fmaxf(sqrtf(tot), 1e-12f);
    }
    __syncthreads();
    {
        const int k = t & 63, w = t >> 6;
        const float sc = invn[k];
        for (int j = 0; j < 64; ++j) {
            int s = w * 64 + j;
            Z[((size_t)b * 256 + s) * 64 + k] = Zb[k * 256 + s] * sc;
        }
    }
}

extern "C" void kernel_launch(void* const* d_in, const int* in_sizes, int n_in,
                              void* d_out, int out_size, void* d_ws, size_t ws_size,
                              hipStream_t stream)
{
    const float* X       = (const float*)d_in[0];
    const float* phi_w   = (const float*)d_in[1];
    const float* phi_g   = (const float*)d_in[2];
    const float* phi_b   = (const float*)d_in[3];
    const float* phi_m   = (const float*)d_in[4];
    const float* phi_v   = (const float*)d_in[5];
    const float* theta_w = (const float*)d_in[6];
    const float* theta_g = (const float*)d_in[7];
    const float* theta_b = (const float*)d_in[8];
    const float* theta_m = (const float*)d_in[9];
    const float* theta_v = (const float*)d_in[10];
    const float* rou_w   = (const float*)d_in[11];
    const float* rou_g   = (const float*)d_in[12];
    const float* rou_b   = (const float*)d_in[13];
    const float* rou_m   = (const float*)d_in[14];
    const float* rou_v   = (const float*)d_in[15];
    const float* val_w   = (const float*)d_in[16];
    const float* val_g   = (const float*)d_in[17];
    const float* val_b   = (const float*)d_in[18];
    const float* val_m   = (const float*)d_in[19];
    const float* val_v   = (const float*)d_in[20];

    float* ws = (float*)d_ws;
    size_t off = 0;
    ushort_t* Xb  = (ushort_t*)(ws + off); off += (size_t)B_ * N_ * C_ / 2;
    ushort_t* Wb  = (ushort_t*)(ws + off); off += 832 * C_ / 2;
    float* be     = ws + off; off += 832;
    float* st2    = ws + off; off += 2 * B_ * 256;
    ushort_t* Pbf = (ushort_t*)(ws + off); off += (size_t)B_ * 64 * N_ / 2;
    ushort_t* Tbf = (ushort_t*)(ws + off); off += (size_t)B_ * 256 * N_ / 2;
    ushort_t* Vbf = (ushort_t*)(ws + off); off += (size_t)B_ * 256 * N_ / 2;
    ushort_t* Rt  = (ushort_t*)(ws + off); off += (size_t)B_ * N_ * 256 / 2;
    ushort_t* Qbf = (ushort_t*)(ws + off); off += (size_t)B_ * 64 * N_ / 2;
    ushort_t* Dbf = (ushort_t*)(ws + off); off += (size_t)B_ * 64 * 256 / 2;
    float* part   = ws + off; off += (size_t)NCHUNK * B_ * TILE_KS;
    float* Qraw   = ws + off; off += (size_t)B_ * N_ * 64;
    float* ZnT    = ws + off; off += (size_t)B_ * TILE_KS;
    float* Nrm    = ws + off; off += B_ * 64;

    float* Zout = (float*)d_out;                  // B*S*K
    float* Qout = Zout + (size_t)B_ * S_ * K_;    // B*N*K

    hipMemsetAsync(Nrm, 0, B_ * 64 * sizeof(float), stream);

    prep_w<<<832, 256, 0, stream>>>(phi_w, phi_g, phi_b, phi_m, phi_v,
                                    theta_w, theta_g, theta_b, theta_m, theta_v,
                                    rou_w, rou_g, rou_b, rou_m, rou_v,
                                    val_w, val_g, val_b, val_m, val_v, Wb, be);
    xpose<<<dim3(N_ / 64, C_ / 64, B_), 256, 0, stream>>>(X, Xb);

    proj_mfma_all<<<3744, 256, 0, stream>>>(Wb, be, Xb, Pbf, Tbf, Vbf, Rt);

    rowstat_n<<<B_ * 256, 256, 0, stream>>>(Tbf, st2);
    softmax_rows<<<B_ * N_ / 4, 256, 0, stream>>>(Rt);

    ks_mfma<<<dim3(NCHUNK, B_), 256, 0, stream>>>(Pbf, Tbf, st2, part);
    chunk_reduce_bf<<<B_ * TILE_KS / 256, 256, 0, stream>>>(part, Dbf);

    qt_mfma<<<36 * B_, 256, 0, stream>>>(Dbf, Rt, Qraw, Nrm);
    q_final<<<dim3(36, B_), 256, 0, stream>>>(Qraw, Nrm, Qout, Qbf);

    ks_mfma<<<dim3(NCHUNK, B_), 256, 0, stream>>>(Qbf, Vbf, (const float*)nullptr, part);
    chunk_reduce_f<<<B_ * TILE_KS / 256, 256, 0, stream>>>(part, ZnT);
    z_final<<<B_, 256, 0, stream>>>(ZnT, Zout);
}

// Round 9
// 289.465 us; speedup vs baseline: 2.6568x; 1.1677x over previous
//
#include <hip/hip_runtime.h>
#include <math.h>

#define B_ 8
#define C_ 256
#define N_ 9216
#define S_ 256
#define K_ 64
#define NCHUNK 36            // 9216 / 256
#define TILE_KS (K_ * S_)    // 16384
#define NC8 (N_ / 8)         // 1152 16B-cells per [*][N] bf16 row

typedef unsigned short ushort_t;
typedef __attribute__((ext_vector_type(8))) short bf16x8;
typedef __attribute__((ext_vector_type(4))) float f32x4;

static __device__ inline ushort_t f2bf(float x) {
    unsigned int u = __float_as_uint(x);
    unsigned int r = (u + 0x7fffu + ((u >> 16) & 1u)) >> 16;
    return (ushort_t)r;
}
static __device__ inline float bf2f(ushort_t u) {
    return __uint_as_float(((unsigned int)u) << 16);
}

// exp-weight one 8-bf16 cell (row-constant max/invsum in s)
static __device__ inline uint4 expcell(uint4 u, float2 s) {
    uint4 r;
    unsigned int* up = (unsigned int*)&u;
    unsigned int* rp = (unsigned int*)&r;
#pragma unroll
    for (int q = 0; q < 4; ++q) {
        unsigned int x = up[q];
        float lo = __uint_as_float((x & 0xffffu) << 16);
        float hi = __uint_as_float(x & 0xffff0000u);
        float el = __expf(lo - s.x) * s.y;
        float eh = __expf(hi - s.x) * s.y;
        rp[q] = (unsigned int)f2bf(el) | ((unsigned int)f2bf(eh) << 16);
    }
    return r;
}

// ---------------- fold BN scale into W, convert to bf16; be[o] = b - m*s
__global__ __launch_bounds__(256) void prep_w(
    const float* __restrict__ phi_w, const float* __restrict__ phi_g, const float* __restrict__ phi_b,
    const float* __restrict__ phi_m, const float* __restrict__ phi_v,
    const float* __restrict__ th_w, const float* __restrict__ th_g, const float* __restrict__ th_b,
    const float* __restrict__ th_m, const float* __restrict__ th_v,
    const float* __restrict__ ro_w, const float* __restrict__ ro_g, const float* __restrict__ ro_b,
    const float* __restrict__ ro_m, const float* __restrict__ ro_v,
    const float* __restrict__ va_w, const float* __restrict__ va_g, const float* __restrict__ va_b,
    const float* __restrict__ va_m, const float* __restrict__ va_v,
    ushort_t* __restrict__ Wb, float* __restrict__ be)
{
    const int o = blockIdx.x;  // 0..831
    const int t = threadIdx.x; // = c
    const float *src, *g, *bb, *mm, *vv; int orel;
    if (o < 64)       { src = phi_w; g = phi_g; bb = phi_b; mm = phi_m; vv = phi_v; orel = o; }
    else if (o < 320) { src = th_w;  g = th_g;  bb = th_b;  mm = th_m;  vv = th_v;  orel = o - 64; }
    else if (o < 576) { src = ro_w;  g = ro_g;  bb = ro_b;  mm = ro_m;  vv = ro_v;  orel = o - 320; }
    else              { src = va_w;  g = va_g;  bb = va_b;  mm = va_m;  vv = va_v;  orel = o - 576; }
    const float s = g[orel] / sqrtf(vv[orel] + 1e-5f);
    Wb[o * C_ + t] = f2bf(src[orel * C_ + t] * s);
    if (t == 0) be[o] = bb[orel] - mm[orel] * s;
}

// ---------------- X[b][c][n] fp32 -> Xb[b][n][c] bf16
__global__ __launch_bounds__(256) void xpose(
    const float* __restrict__ X, ushort_t* __restrict__ Xb)
{
    __shared__ float T[64][65];
    const int b = blockIdx.z, c0 = blockIdx.y * 64, n0 = blockIdx.x * 64;
    const int t = threadIdx.x;
#pragma unroll
    for (int p = 0; p < 4; ++p) {
        int c = p * 16 + (t >> 4), nn = (t & 15) * 4;
        float4 v = *(const float4*)&X[((size_t)b * C_ + c0 + c) * N_ + n0 + nn];
        T[c][nn] = v.x; T[c][nn + 1] = v.y; T[c][nn + 2] = v.z; T[c][nn + 3] = v.w;
    }
    __syncthreads();
#pragma unroll
    for (int p = 0; p < 4; ++p) {
        int nn = p * 16 + (t >> 4), cl = (t & 15) * 4;
        ushort4 u;
        u.x = f2bf(T[cl][nn]); u.y = f2bf(T[cl + 1][nn]);
        u.z = f2bf(T[cl + 2][nn]); u.w = f2bf(T[cl + 3][nn]);
        *(ushort4*)&Xb[((size_t)b * N_ + n0 + nn) * C_ + c0 + cl] = u;
    }
}

// ---------------- fused bf16-MFMA projection, ALL 13 o-tiles, bf16 outputs.
// R8 diagnosis: latency-bound, 2 blocks/CU (64KB LDS), all pipes <10%.
// This version: W direct global->reg per stage (L2-hot, no LDS), X-only LDS
// 32KB double-buffered 2x16KB (BK=32, 8 stages), ONE barrier per stage.
// Occupancy target: 4+ blocks/CU. XCD-bijective o-fastest decode kept (R8: FETCH 298->49MB).
__global__ __launch_bounds__(256) void proj_mfma_all(
    const ushort_t* __restrict__ Wb, const float* __restrict__ be,
    const ushort_t* __restrict__ Xb,
    ushort_t* __restrict__ Pbf, ushort_t* __restrict__ Tbf,
    ushort_t* __restrict__ Vbf, ushort_t* __restrict__ Rt)
{
    __shared__ short sm[16384];  // 32 KB: X dbuf, 1024 cells per buffer (16B cells)
    const int t = threadIdx.x;
    const int l = t & 63, w = t >> 6;
    const int idx = blockIdx.x;          // 0..3743
    const int xcd = idx & 7, pos = idx >> 3;
    const int vid = xcd * 468 + pos;     // 468 = 36*13 blocks per XCD chunk
    const int ot  = vid % 13;
    const int r   = vid / 13;            // 0..287
    const int b   = r / 36;
    const int n0  = (r % 36) * 256;
    const int o0  = ot * 64;

    const uint4* Xv = (const uint4*)Xb;
    uint4* smv = (uint4*)sm;
    const bf16x8* smX = (const bf16x8*)sm;

    // per-lane W fragment row pointers: A[os] at stage st = *(pW[os] + st*64B)
    const char* pW[4];
#pragma unroll
    for (int os = 0; os < 4; ++os)
        pW[os] = (const char*)Wb + ((size_t)(o0 + os * 16 + (l & 15)) * 32 + (l >> 4)) * 16;

    // prologue: load X stage 0 (cells: [s(16)][g8(4)][ni(16)], 4 cells/thread)
    uint4 xreg[4];
#pragma unroll
    for (int i = 0; i < 4; ++i) {
        int cell = i * 256 + t;
        int s = cell >> 6, g8 = (cell >> 4) & 3, ni = cell & 15;
        xreg[i] = Xv[(size_t)(b * N_ + n0 + s * 16 + ni) * 32 + g8];
    }

    f32x4 zr = {0.f, 0.f, 0.f, 0.f};
    f32x4 acc[4][4];
#pragma unroll
    for (int i = 0; i < 4; ++i)
#pragma unroll
        for (int j = 0; j < 4; ++j) acc[i][j] = zr;

    for (int st = 0; st < 8; ++st) {
        const int buf = (st & 1) * 1024;
        // write current stage into its buffer (other buffer may still be read by peers)
#pragma unroll
        for (int i = 0; i < 4; ++i) smv[buf + i * 256 + t] = xreg[i];
        __syncthreads();
        // issue next stage's global loads (hide under MFMA below)
        if (st < 7) {
#pragma unroll
            for (int i = 0; i < 4; ++i) {
                int cell = i * 256 + t;
                int s = cell >> 6, g8 = (cell >> 4) & 3, ni = cell & 15;
                xreg[i] = Xv[(size_t)(b * N_ + n0 + s * 16 + ni) * 32 + (st + 1) * 4 + g8];
            }
        }
        // W fragments for this K-stage (L1/L2-hot)
        bf16x8 A[4];
#pragma unroll
        for (int os = 0; os < 4; ++os)
            A[os] = *(const bf16x8*)(pW[os] + st * 64);
        bf16x8 Bf[4];
#pragma unroll
        for (int j = 0; j < 4; ++j)
            Bf[j] = smX[buf + (w * 4 + j) * 64 + (l >> 4) * 16 + (l & 15)];
#pragma unroll
        for (int os = 0; os < 4; ++os)
#pragma unroll
            for (int j = 0; j < 4; ++j)
                acc[os][j] = __builtin_amdgcn_mfma_f32_16x16x32_bf16(A[os], Bf[j], acc[os][j], 0, 0, 0);
    }

    // epilogue (block-uniform branch on o0); all tiles fit 32KB
    if (o0 >= 320 && o0 < 576) {
        // rou -> Rt[b][n][256s] transposed, two 32-n-row halves; per-wave [32][72] bf16
        const int od = o0 - 320;
        ushort_t* Tt = (ushort_t*)sm + w * (32 * 72);   // 4608B/wave, 18432B total
#pragma unroll
        for (int half = 0; half < 2; ++half) {
            __syncthreads();
#pragma unroll
            for (int jj = 0; jj < 2; ++jj) {
                const int j = half * 2 + jj;
#pragma unroll
                for (int os = 0; os < 4; ++os)
#pragma unroll
                    for (int r2 = 0; r2 < 4; ++r2) {
                        const int scol = os * 16 + (l >> 4) * 4 + r2;
                        const float bias = be[o0 + scol];
                        Tt[(jj * 16 + (l & 15)) * 72 + scol] = f2bf(fmaxf(acc[os][j][r2] + bias, 0.f));
                    }
            }
            __syncthreads();
#pragma unroll
            for (int p = 0; p < 4; ++p) {
                const int lrow = p * 8 + (l >> 3);   // 0..31
                uint4 v = *(const uint4*)&Tt[lrow * 72 + (l & 7) * 8];
                *(uint4*)&Rt[((size_t)b * N_ + n0 + w * 64 + half * 32 + lrow) * 256 + od + (l & 7) * 8] = v;
            }
        }
    } else {
        ushort_t* dst; int od, osz;
        if (o0 < 64)       { dst = Pbf; od = o0;       osz = 64;  }
        else if (o0 < 320) { dst = Tbf; od = o0 - 64;  osz = 256; }
        else               { dst = Vbf; od = o0 - 576; osz = 256; }
        ushort_t* Tw = (ushort_t*)sm + w * (32 * 68);  // 4352B/wave, 17408B total
#pragma unroll
        for (int half = 0; half < 2; ++half) {
            __syncthreads();
#pragma unroll
            for (int osl = 0; osl < 2; ++osl) {
                const int os = half * 2 + osl;
#pragma unroll
                for (int r2 = 0; r2 < 4; ++r2) {
                    const int lrow = osl * 16 + (l >> 4) * 4 + r2;
                    const int orow = half * 32 + lrow;
                    const float bias = be[o0 + orow];
#pragma unroll
                    for (int j = 0; j < 4; ++j)
                        Tw[lrow * 68 + j * 16 + (l & 15)] = f2bf(fmaxf(acc[os][j][r2] + bias, 0.f));
                }
            }
            __syncthreads();
#pragma unroll
            for (int i = 0; i < 8; ++i) {
                const int lrow = i * 4 + (l >> 4);
                ushort4 v = *(const ushort4*)&Tw[lrow * 68 + (l & 15) * 4];
                *(ushort4*)&dst[((size_t)(b * osz + od + half * 32 + lrow)) * N_ + n0 + w * 64 + (l & 15) * 4] = v;
            }
        }
    }
}

// ---------------- theta row stats: st2[row] = (max, 1/sum(exp(x-max))) over N
__global__ __launch_bounds__(256) void rowstat_n(
    const ushort_t* __restrict__ T, float* __restrict__ st2)
{
    const int row = blockIdx.x;  // b*256 + s
    const ushort4* p = (const ushort4*)(T + (size_t)row * N_);
    const int t = threadIdx.x;
    float v[36];
    float mx = -INFINITY;
#pragma unroll
    for (int i = 0; i < 9; ++i) {
        ushort4 u = p[t + i * 256];
        v[i * 4 + 0] = bf2f(u.x); v[i * 4 + 1] = bf2f(u.y);
        v[i * 4 + 2] = bf2f(u.z); v[i * 4 + 3] = bf2f(u.w);
        mx = fmaxf(mx, fmaxf(fmaxf(v[i * 4], v[i * 4 + 1]), fmaxf(v[i * 4 + 2], v[i * 4 + 3])));
    }
    __shared__ float red[256];
    red[t] = mx; __syncthreads();
    for (int s2 = 128; s2 > 0; s2 >>= 1) {
        if (t < s2) red[t] = fmaxf(red[t], red[t + s2]);
        __syncthreads();
    }
    mx = red[0]; __syncthreads();
    float sum = 0.f;
#pragma unroll
    for (int i = 0; i < 36; ++i) sum += __expf(v[i] - mx);
    red[t] = sum; __syncthreads();
    for (int s2 = 128; s2 > 0; s2 >>= 1) {
        if (t < s2) red[t] += red[t + s2];
        __syncthreads();
    }
    if (t == 0) ((float2*)st2)[row] = make_float2(mx, 1.0f / red[0]);
}

// ---------------- softmax over contiguous rows of 256 bf16 (rou: over s at fixed n), in place
__global__ __launch_bounds__(256) void softmax_rows(ushort_t* __restrict__ R)
{
    const size_t row = (size_t)blockIdx.x * 4 + (threadIdx.x >> 6);
    const int l = threadIdx.x & 63;
    ushort4* p = (ushort4*)(R + row * 256);
    ushort4 u = p[l];
    float f0 = bf2f(u.x), f1 = bf2f(u.y), f2 = bf2f(u.z), f3 = bf2f(u.w);
    float mx = fmaxf(fmaxf(f0, f1), fmaxf(f2, f3));
#pragma unroll
    for (int m = 1; m < 64; m <<= 1) mx = fmaxf(mx, __shfl_xor(mx, m));
    f0 = __expf(f0 - mx); f1 = __expf(f1 - mx); f2 = __expf(f2 - mx); f3 = __expf(f3 - mx);
    float s = f0 + f1 + f2 + f3;
#pragma unroll
    for (int m = 1; m < 64; m <<= 1) s += __shfl_xor(s, m);
    const float inv = 1.0f / s;
    u.x = f2bf(f0 * inv); u.y = f2bf(f1 * inv); u.z = f2bf(f2 * inv); u.w = f2bf(f3 * inv);
    p[l] = u;
}

// ---------------- MFMA: P[chunk][b][k][s] = sum_{n in chunk} A[b,k,n] * w(Bm)[b,s,n]
__global__ __launch_bounds__(256) void ks_mfma(
    const ushort_t* __restrict__ A, const ushort_t* __restrict__ Bm,
    const float* __restrict__ st2, float* __restrict__ P)
{
    __shared__ short sm[32768];
    const int t = threadIdx.x;
    const int l = t & 63, w = t >> 6;
    const int chunk = blockIdx.x, b = blockIdx.y;
    const int ccell = chunk * 32;

    const uint4* Av = (const uint4*)A;
    const uint4* Bv = (const uint4*)Bm;
    const float2* S2 = (const float2*)st2;
    uint4* smv = (uint4*)sm;
    const bool doexp = (st2 != nullptr);

    uint4 wreg[8], xreg[8];
    float2 sreg[8];
#pragma unroll
    for (int i = 0; i < 8; ++i) {
        int cell = i * 256 + t;
        int osub = cell >> 9, g = (cell >> 4) & 31, oi = cell & 15;
        wreg[i] = Av[(size_t)(b * 64 + osub * 16 + oi) * NC8 + ccell + g];
    }
#pragma unroll
    for (int i = 0; i < 8; ++i) {
        int cell = i * 256 + t;
        int s = cell >> 7, g8 = (cell >> 4) & 7, ni = cell & 15;
        int row = s * 16 + ni;
        xreg[i] = Bv[(size_t)(b * 256 + row) * NC8 + ccell + g8];
        if (doexp) sreg[i] = S2[b * 256 + row];
    }
#pragma unroll
    for (int i = 0; i < 8; ++i) smv[i * 256 + t] = wreg[i];
#pragma unroll
    for (int i = 0; i < 8; ++i) smv[2048 + i * 256 + t] = doexp ? expcell(xreg[i], sreg[i]) : xreg[i];
    __syncthreads();

    f32x4 zr = {0.f, 0.f, 0.f, 0.f};
    f32x4 acc[4][4];
#pragma unroll
    for (int i = 0; i < 4; ++i)
#pragma unroll
        for (int j = 0; j < 4; ++j) acc[i][j] = zr;

    const bf16x8* smW = (const bf16x8*)sm;
    const bf16x8* smX = (const bf16x8*)(sm + 16384);

    for (int st = 0; st < 4; ++st) {
        if (st < 3) {
#pragma unroll
            for (int i = 0; i < 8; ++i) {
                int cell = i * 256 + t;
                int s = cell >> 7, g8 = (cell >> 4) & 7, ni = cell & 15;
                int row = s * 16 + ni;
                xreg[i] = Bv[(size_t)(b * 256 + row) * NC8 + ccell + (st + 1) * 8 + g8];
                if (doexp) sreg[i] = S2[b * 256 + row];
            }
        }
#pragma unroll
        for (int kgl = 0; kgl < 2; ++kgl) {
            const int kg = st * 2 + kgl;
            bf16x8 Af[4], Bf[4];
#pragma unroll
            for (int os = 0; os < 4; ++os)
                Af[os] = smW[(os * 32 + kg * 4 + (l >> 4)) * 16 + (l & 15)];
#pragma unroll
            for (int j = 0; j < 4; ++j)
                Bf[j] = smX[((w * 4 + j) * 8 + kgl * 4 + (l >> 4)) * 16 + (l & 15)];
#pragma unroll
            for (int os = 0; os < 4; ++os)
#pragma unroll
                for (int j = 0; j < 4; ++j)
                    acc[os][j] = __builtin_amdgcn_mfma_f32_16x16x32_bf16(Af[os], Bf[j], acc[os][j], 0, 0, 0);
        }
        __syncthreads();
        if (st < 3) {
#pragma unroll
            for (int i = 0; i < 8; ++i) smv[2048 + i * 256 + t] = doexp ? expcell(xreg[i], sreg[i]) : xreg[i];
            __syncthreads();
        }
    }

    float* Pb = P + ((size_t)(chunk * B_ + b)) * TILE_KS;
#pragma unroll
    for (int os = 0; os < 4; ++os)
#pragma unroll
        for (int r = 0; r < 4; ++r) {
            const int k = os * 16 + (l >> 4) * 4 + r;
#pragma unroll
            for (int j = 0; j < 4; ++j)
                Pb[k * 256 + (w * 4 + j) * 16 + (l & 15)] = acc[os][j][r];
        }
}

// ---------------- MFMA: Qraw[b][n][k] = sum_s Dbf[b,k,s] * Rsm[b,n,s]; fused nrm2 atomics
__global__ __launch_bounds__(256) void qt_mfma(
    const ushort_t* __restrict__ Dbf,  // [b][64][256]
    const ushort_t* __restrict__ Rsm,  // [b][N][256]
    float* __restrict__ Qraw,          // [b][N][64]
    float* __restrict__ Nrm)           // [b][64], pre-zeroed
{
    __shared__ short sm[32768];
    const int t = threadIdx.x;
    const int l = t & 63, w = t >> 6;
    const int b = blockIdx.x / 36;
    const int n0 = (blockIdx.x % 36) * 256;

    const uint4* Av = (const uint4*)Dbf;
    const uint4* Xv = (const uint4*)Rsm;
    uint4* smv = (uint4*)sm;

    uint4 wreg[8], xreg[8];
#pragma unroll
    for (int i = 0; i < 8; ++i) {
        int cell = i * 256 + t;
        int osub = cell >> 9, g = (cell >> 4) & 31, oi = cell & 15;
        wreg[i] = Av[(size_t)(b * 64 + osub * 16 + oi) * 32 + g];
    }
#pragma unroll
    for (int i = 0; i < 8; ++i) {
        int cell = i * 256 + t;
        int s = cell >> 7, g8 = (cell >> 4) & 7, ni = cell & 15;
        xreg[i] = Xv[((size_t)b * N_ + n0 + s * 16 + ni) * 32 + g8];
    }
#pragma unroll
    for (int i = 0; i < 8; ++i) smv[i * 256 + t] = wreg[i];
#pragma unroll
    for (int i = 0; i < 8; ++i) smv[2048 + i * 256 + t] = xreg[i];
    __syncthreads();

    f32x4 zr = {0.f, 0.f, 0.f, 0.f};
    f32x4 acc[4][4];
#pragma unroll
    for (int i = 0; i < 4; ++i)
#pragma unroll
        for (int j = 0; j < 4; ++j) acc[i][j] = zr;

    const bf16x8* smW = (const bf16x8*)sm;
    const bf16x8* smX = (const bf16x8*)(sm + 16384);

    for (int st = 0; st < 4; ++st) {
        if (st < 3) {
#pragma unroll
            for (int i = 0; i < 8; ++i) {
                int cell = i * 256 + t;
                int s = cell >> 7, g8 = (cell >> 4) & 7, ni = cell & 15;
                xreg[i] = Xv[((size_t)b * N_ + n0 + s * 16 + ni) * 32 + (st + 1) * 8 + g8];
            }
        }
#pragma unroll
        for (int kgl = 0; kgl < 2; ++kgl) {
            const int kg = st * 2 + kgl;
            bf16x8 Af[4], Bf[4];
#pragma unroll
            for (int os = 0; os < 4; ++os)
                Af[os] = smW[(os * 32 + kg * 4 + (l >> 4)) * 16 + (l & 15)];
#pragma unroll
            for (int j = 0; j < 4; ++j)
                Bf[j] = smX[((w * 4 + j) * 8 + kgl * 4 + (l >> 4)) * 16 + (l & 15)];
#pragma unroll
            for (int os = 0; os < 4; ++os)
#pragma unroll
                for (int j = 0; j < 4; ++j)
                    acc[os][j] = __builtin_amdgcn_mfma_f32_16x16x32_bf16(Af[os], Bf[j], acc[os][j], 0, 0, 0);
        }
        __syncthreads();
        if (st < 3) {
#pragma unroll
            for (int i = 0; i < 8; ++i) smv[2048 + i * 256 + t] = xreg[i];
            __syncthreads();
        }
    }

    // epilogue: nrm2 partials + [n][k] transposed fp32 stores
    float* snrm = (float*)sm + 9216;
    __syncthreads();
    if (t < 64) snrm[t] = 0.f;
    __syncthreads();
#pragma unroll
    for (int os = 0; os < 4; ++os)
#pragma unroll
        for (int r = 0; r < 4; ++r) {
            float p = 0.f;
#pragma unroll
            for (int j = 0; j < 4; ++j) p = fmaf(acc[os][j][r], acc[os][j][r], p);
#pragma unroll
            for (int m = 1; m < 16; m <<= 1) p += __shfl_xor(p, m);
            if ((l & 15) == 0) atomicAdd(&snrm[os * 16 + (l >> 4) * 4 + r], p);
        }
    float* Tw = (float*)sm + w * 2304;  // per-wave [32][72]
#pragma unroll
    for (int h = 0; h < 2; ++h) {
        __syncthreads();
#pragma unroll
        for (int os = 0; os < 4; ++os)
#pragma unroll
            for (int r = 0; r < 4; ++r) {
                const int kcol = os * 16 + (l >> 4) * 4 + r;
#pragma unroll
                for (int jj = 0; jj < 2; ++jj)
                    Tw[(jj * 16 + (l & 15)) * 72 + kcol] = acc[os][h * 2 + jj][r];
            }
        __syncthreads();
#pragma unroll
        for (int i = 0; i < 8; ++i) {
            const int lrow = i * 4 + (l >> 4);
            f32x4 v = *(const f32x4*)&Tw[lrow * 72 + (l & 15) * 4];
            *(f32x4*)&Qraw[((size_t)b * N_ + n0 + w * 64 + h * 32 + lrow) * 64 + (l & 15) * 4] = v;
        }
    }
    __syncthreads();
    if (t < 64) atomicAdd(&Nrm[b * 64 + t], snrm[t]);
}

// ---------------- partial-sum reductions over NCHUNK
__global__ __launch_bounds__(256) void chunk_reduce_bf(
    const float* __restrict__ P, ushort_t* __restrict__ outb)
{
    const int i = blockIdx.x * 256 + threadIdx.x;
    float s = 0.f;
#pragma unroll
    for (int c = 0; c < NCHUNK; ++c) s += P[(size_t)c * (B_ * TILE_KS) + i];
    outb[i] = f2bf(s);
}
__global__ __launch_bounds__(256) void chunk_reduce_f(
    const float* __restrict__ P, float* __restrict__ outf)
{
    const int i = blockIdx.x * 256 + threadIdx.x;
    float s = 0.f;
#pragma unroll
    for (int c = 0; c < NCHUNK; ++c) s += P[(size_t)c * (B_ * TILE_KS) + i];
    outf[i] = s;
}

// ---------------- Q = softmax_k(Qraw * invn); write Qout[b][n][k] fp32 + Qbf[b][k][n] bf16
__global__ __launch_bounds__(256) void q_final(
    const float* __restrict__ Qraw, const float* __restrict__ Nrm,
    float* __restrict__ Qout, ushort_t* __restrict__ Qbf)
{
    __shared__ ushort_t Tq[64 * 256];
    __shared__ float invn[64];
    const int b = blockIdx.y;
    const int n0 = blockIdx.x * 256;
    const int t = threadIdx.x;
    const int l = t & 63, w = t >> 6;
    if (t < 64) invn[t] = 1.0f / fmaxf(sqrtf(Nrm[b * 64 + t]), 1e-12f);
    __syncthreads();
    const size_t base = ((size_t)b * N_ + n0 + t) * 64;
    float q[64];
#pragma unroll
    for (int kk = 0; kk < 16; ++kk) {
        f32x4 v = *(const f32x4*)&Qraw[base + kk * 4];
        q[kk * 4 + 0] = v[0]; q[kk * 4 + 1] = v[1]; q[kk * 4 + 2] = v[2]; q[kk * 4 + 3] = v[3];
    }
    float mx = -INFINITY;
#pragma unroll
    for (int k = 0; k < 64; ++k) { q[k] *= invn[k]; mx = fmaxf(mx, q[k]); }
    float sum = 0.f;
#pragma unroll
    for (int k = 0; k < 64; ++k) { q[k] = __expf(q[k] - mx); sum += q[k]; }
    const float inv = 1.0f / sum;
#pragma unroll
    for (int kk = 0; kk < 16; ++kk) {
        f32x4 v = {q[kk * 4] * inv, q[kk * 4 + 1] * inv, q[kk * 4 + 2] * inv, q[kk * 4 + 3] * inv};
        *(f32x4*)&Qout[base + kk * 4] = v;
        q[kk * 4] = v[0]; q[kk * 4 + 1] = v[1]; q[kk * 4 + 2] = v[2]; q[kk * 4 + 3] = v[3];
    }
#pragma unroll
    for (int k = 0; k < 64; ++k) Tq[k * 256 + t] = f2bf(q[k]);
    __syncthreads();
#pragma unroll
    for (int kk = 0; kk < 16; ++kk) {
        const int k = kk * 4 + w;
        ushort4 v = *(const ushort4*)&Tq[k * 256 + l * 4];
        *(ushort4*)&Qbf[((size_t)b * 64 + k) * N_ + n0 + l * 4] = v;
    }
}

// ---------------- Z[b,s,k] = ZnT[b,k,s] / l2norm over s (qsum cancels in l2norm)
__global__ __launch_bounds__(256) void z_final(
    const float* __restrict__ ZnT, float* __restrict__ Z)
{
    __shared__ float red[256];
    __shared__ float invn[64];
    const int b = blockIdx.x;
    const int t = threadIdx.x;
    const float* Zb = ZnT + (size_t)b * TILE_KS;
    {
        const int k = t >> 2, qq = t & 3;
        float ss = 0.f;
        for (int j = 0; j < 64; ++j) {
            float v = Zb[k * 256 + qq * 64 + j];
            ss = fmaf(v, v, ss);
        }
        red[t] = ss;
    }
    __syncthreads();
    if ((t & 3) == 0) {
        float tot = red[t] + red[t + 1] + red[t + 2] + red[t + 3];
        invn[t >> 2] = 1.0f / fmaxf(sqrtf(tot), 1e-12f);
    }
    __syncthreads();
    {
        const int k = t & 63, w = t >> 6;
        const float sc = invn[k];
        for (int j = 0; j < 64; ++j) {
            int s = w * 64 + j;
            Z[((size_t)b * 256 + s) * 64 + k] = Zb[k * 256 + s] * sc;
        }
    }
}

extern "C" void kernel_launch(void* const* d_in, const int* in_sizes, int n_in,
                              void* d_out, int out_size, void* d_ws, size_t ws_size,
                              hipStream_t stream)
{
    const float* X       = (const float*)d_in[0];
    const float* phi_w   = (const float*)d_in[1];
    const float* phi_g   = (const float*)d_in[2];
    const float* phi_b   = (const float*)d_in[3];
    const float* phi_m   = (const float*)d_in[4];
    const float* phi_v   = (const float*)d_in[5];
    const float* theta_w = (const float*)d_in[6];
    const float* theta_g = (const float*)d_in[7];
    const float* theta_b = (const float*)d_in[8];
    const float* theta_m = (const float*)d_in[9];
    const float* theta_v = (const float*)d_in[10];
    const float* rou_w   = (const float*)d_in[11];
    const float* rou_g   = (const float*)d_in[12];
    const float* rou_b   = (const float*)d_in[13];
    const float* rou_m   = (const float*)d_in[14];
    const float* rou_v   = (const float*)d_in[15];
    const float* val_w   = (const float*)d_in[16];
    const float* val_g   = (const float*)d_in[17];
    const float* val_b   = (const float*)d_in[18];
    const float* val_m   = (const float*)d_in[19];
    const float* val_v   = (const float*)d_in[20];

    float* ws = (float*)d_ws;
    size_t off = 0;
    ushort_t* Xb  = (ushort_t*)(ws + off); off += (size_t)B_ * N_ * C_ / 2;
    ushort_t* Wb  = (ushort_t*)(ws + off); off += 832 * C_ / 2;
    float* be     = ws + off; off += 832;
    float* st2    = ws + off; off += 2 * B_ * 256;
    ushort_t* Pbf = (ushort_t*)(ws + off); off += (size_t)B_ * 64 * N_ / 2;
    ushort_t* Tbf = (ushort_t*)(ws + off); off += (size_t)B_ * 256 * N_ / 2;
    ushort_t* Vbf = (ushort_t*)(ws + off); off += (size_t)B_ * 256 * N_ / 2;
    ushort_t* Rt  = (ushort_t*)(ws + off); off += (size_t)B_ * N_ * 256 / 2;
    ushort_t* Qbf = (ushort_t*)(ws + off); off += (size_t)B_ * 64 * N_ / 2;
    ushort_t* Dbf = (ushort_t*)(ws + off); off += (size_t)B_ * 64 * 256 / 2;
    float* part   = ws + off; off += (size_t)NCHUNK * B_ * TILE_KS;
    float* Qraw   = ws + off; off += (size_t)B_ * N_ * 64;
    float* ZnT    = ws + off; off += (size_t)B_ * TILE_KS;
    float* Nrm    = ws + off; off += B_ * 64;

    float* Zout = (float*)d_out;                  // B*S*K
    float* Qout = Zout + (size_t)B_ * S_ * K_;    // B*N*K

    hipMemsetAsync(Nrm, 0, B_ * 64 * sizeof(float), stream);

    prep_w<<<832, 256, 0, stream>>>(phi_w, phi_g, phi_b, phi_m, phi_v,
                                    theta_w, theta_g, theta_b, theta_m, theta_v,
                                    rou_w, rou_g, rou_b, rou_m, rou_v,
                                    val_w, val_g, val_b, val_m, val_v, Wb, be);
    xpose<<<dim3(N_ / 64, C_ / 64, B_), 256, 0, stream>>>(X, Xb);

    proj_mfma_all<<<3744, 256, 0, stream>>>(Wb, be, Xb, Pbf, Tbf, Vbf, Rt);

    rowstat_n<<<B_ * 256, 256, 0, stream>>>(Tbf, st2);
    softmax_rows<<<B_ * N_ / 4, 256, 0, stream>>>(Rt);

    ks_mfma<<<dim3(NCHUNK, B_), 256, 0, stream>>>(Pbf, Tbf, st2, part);
    chunk_reduce_bf<<<B_ * TILE_KS / 256, 256, 0, stream>>>(part, Dbf);

    qt_mfma<<<36 * B_, 256, 0, stream>>>(Dbf, Rt, Qraw, Nrm);
    q_final<<<dim3(36, B_), 256, 0, stream>>>(Qraw, Nrm, Qout, Qbf);

    ks_mfma<<<dim3(NCHUNK, B_), 256, 0, stream>>>(Qbf, Vbf, (const float*)nullptr, part);
    chunk_reduce_f<<<B_ * TILE_KS / 256, 256, 0, stream>>>(part, ZnT);
    z_final<<<B_, 256, 0, stream>>>(ZnT, Zout);
}

// Round 10
// 232.680 us; speedup vs baseline: 3.3052x; 1.2440x over previous
//
#include <hip/hip_runtime.h>
#include <math.h>

#define B_ 8
#define C_ 256
#define N_ 9216
#define S_ 256
#define K_ 64
#define NCHUNK 36            // 9216 / 256
#define TILE_KS (K_ * S_)    // 16384
#define NC8 (N_ / 8)         // 1152 16B-cells per [*][N] bf16 row

typedef unsigned short ushort_t;
typedef __attribute__((ext_vector_type(8))) short bf16x8;
typedef __attribute__((ext_vector_type(4))) float f32x4;

static __device__ inline ushort_t f2bf(float x) {
    unsigned int u = __float_as_uint(x);
    unsigned int r = (u + 0x7fffu + ((u >> 16) & 1u)) >> 16;
    return (ushort_t)r;
}
static __device__ inline float bf2f(ushort_t u) {
    return __uint_as_float(((unsigned int)u) << 16);
}

// exp-weight one 8-bf16 cell (row-constant max/invsum in s)
static __device__ inline uint4 expcell(uint4 u, float2 s) {
    uint4 r;
    unsigned int* up = (unsigned int*)&u;
    unsigned int* rp = (unsigned int*)&r;
#pragma unroll
    for (int q = 0; q < 4; ++q) {
        unsigned int x = up[q];
        float lo = __uint_as_float((x & 0xffffu) << 16);
        float hi = __uint_as_float(x & 0xffff0000u);
        float el = __expf(lo - s.x) * s.y;
        float eh = __expf(hi - s.x) * s.y;
        rp[q] = (unsigned int)f2bf(el) | ((unsigned int)f2bf(eh) << 16);
    }
    return r;
}

// ---------------- fold BN scale into W -> bf16 in STAGING-COALESCED layout Wt.
// Wt element for (o,c): ot=o>>6, st=c>>5, os=(o>>4)&3, lane=((c>>3)&3)*16+(o&15), e=c&7
// flat = (((ot*8+st)*4+os)*64 + lane)*8 + e.  proj reads 16B/lane consecutive.
__global__ __launch_bounds__(256) void prep_w(
    const float* __restrict__ phi_w, const float* __restrict__ phi_g, const float* __restrict__ phi_b,
    const float* __restrict__ phi_m, const float* __restrict__ phi_v,
    const float* __restrict__ th_w, const float* __restrict__ th_g, const float* __restrict__ th_b,
    const float* __restrict__ th_m, const float* __restrict__ th_v,
    const float* __restrict__ ro_w, const float* __restrict__ ro_g, const float* __restrict__ ro_b,
    const float* __restrict__ ro_m, const float* __restrict__ ro_v,
    const float* __restrict__ va_w, const float* __restrict__ va_g, const float* __restrict__ va_b,
    const float* __restrict__ va_m, const float* __restrict__ va_v,
    ushort_t* __restrict__ Wt, float* __restrict__ be)
{
    const int o = blockIdx.x;  // 0..831
    const int t = threadIdx.x; // = c
    const float *src, *g, *bb, *mm, *vv; int orel;
    if (o < 64)       { src = phi_w; g = phi_g; bb = phi_b; mm = phi_m; vv = phi_v; orel = o; }
    else if (o < 320) { src = th_w;  g = th_g;  bb = th_b;  mm = th_m;  vv = th_v;  orel = o - 64; }
    else if (o < 576) { src = ro_w;  g = ro_g;  bb = ro_b;  mm = ro_m;  vv = ro_v;  orel = o - 320; }
    else              { src = va_w;  g = va_g;  bb = va_b;  mm = va_m;  vv = va_v;  orel = o - 576; }
    const float s = g[orel] / sqrtf(vv[orel] + 1e-5f);
    const int ot = o >> 6, os = (o >> 4) & 3, st = t >> 5;
    const size_t flat = ((((size_t)ot * 8 + st) * 4 + os) * 64 + ((t >> 3) & 3) * 16 + (o & 15)) * 8 + (t & 7);
    Wt[flat] = f2bf(src[orel * C_ + t] * s);
    if (t == 0) be[o] = bb[orel] - mm[orel] * s;
}

// ---------------- X[b][c][n] fp32 -> Xs bf16 in STAGING-COALESCED layout:
// Xs cell for (b,n,c): nt=n>>8, nr=n&255, st=c>>5, g8=(c>>3)&3, e=c&7
// flat = (((b*36+nt)*8+st)*1024 + (nr>>4)*64 + g8*16 + (nr&15))*8 + e.
__global__ __launch_bounds__(256) void xpose(
    const float* __restrict__ X, ushort_t* __restrict__ Xs)
{
    __shared__ float T[64][65];
    const int b = blockIdx.z, c0 = blockIdx.y * 64, n0 = blockIdx.x * 64;
    const int t = threadIdx.x;
#pragma unroll
    for (int p = 0; p < 4; ++p) {
        int c = p * 16 + (t >> 4), nn = (t & 15) * 4;
        float4 v = *(const float4*)&X[((size_t)b * C_ + c0 + c) * N_ + n0 + nn];
        T[c][nn] = v.x; T[c][nn + 1] = v.y; T[c][nn + 2] = v.z; T[c][nn + 3] = v.w;
    }
    __syncthreads();
#pragma unroll
    for (int p = 0; p < 4; ++p) {
        int nn = p * 16 + (t >> 4), cl = (t & 15) * 4;
        ushort4 u;
        u.x = f2bf(T[cl][nn]); u.y = f2bf(T[cl + 1][nn]);
        u.z = f2bf(T[cl + 2][nn]); u.w = f2bf(T[cl + 3][nn]);
        const int n = n0 + nn, c = c0 + cl;
        const int nt = n >> 8, nr = n & 255;
        const int st = c >> 5, g8 = (c >> 3) & 3, e = c & 7;  // e in {0,4}
        const size_t base = ((((size_t)b * 36 + nt) * 8 + st) * 1024
                             + (nr >> 4) * 64 + g8 * 16 + (nr & 15)) * 8 + e;
        *(ushort4*)&Xs[base] = u;
    }
}

// ---------------- fused bf16-MFMA projection, ALL 13 o-tiles, bf16 outputs.
// R9 diagnosis: per-stage W and X loads were 64-line GATHERS (512B row stride) ->
// memory-pipe tag saturation, 90% idle. This version: both streams pre-relayouted
// (Wt, Xs) so every load is lane-consecutive 16B = coalesced 1KB/instr.
// X-only LDS 32KB dbuf (BK=32, 8 stages, 1 barrier/stage); W direct global->reg (L2-hot).
__global__ __launch_bounds__(256) void proj_mfma_all(
    const ushort_t* __restrict__ Wt, const float* __restrict__ be,
    const ushort_t* __restrict__ Xs,
    ushort_t* __restrict__ Pbf, ushort_t* __restrict__ Tbf,
    ushort_t* __restrict__ Vbf, ushort_t* __restrict__ Rt)
{
    __shared__ short sm[16384];  // 32 KB: X dbuf, 1024 cells per buffer (16B cells)
    const int t = threadIdx.x;
    const int l = t & 63, w = t >> 6;
    const int idx = blockIdx.x;          // 0..3743
    const int xcd = idx & 7, pos = idx >> 3;
    const int vid = xcd * 468 + pos;     // 468 = 36*13 blocks per XCD chunk
    const int ot  = vid % 13;
    const int r   = vid / 13;            // 0..287
    const int b   = r / 36;
    const int nt  = r % 36;
    const int n0  = nt * 256;
    const int o0  = ot * 64;

    const uint4* Xv = (const uint4*)Xs;
    const bf16x8* Wv = (const bf16x8*)Wt;
    uint4* smv = (uint4*)sm;
    const bf16x8* smX = (const bf16x8*)sm;
    const size_t xbase = ((size_t)b * 36 + nt) * 8 * 1024;  // cell base for this (b,nt)

    // prologue: load X stage 0 (coalesced: cells t, t+256, t+512, t+768)
    uint4 xreg[4];
#pragma unroll
    for (int i = 0; i < 4; ++i)
        xreg[i] = Xv[xbase + i * 256 + t];

    f32x4 zr = {0.f, 0.f, 0.f, 0.f};
    f32x4 acc[4][4];
#pragma unroll
    for (int i = 0; i < 4; ++i)
#pragma unroll
        for (int j = 0; j < 4; ++j) acc[i][j] = zr;

    for (int st = 0; st < 8; ++st) {
        const int buf = (st & 1) * 1024;
#pragma unroll
        for (int i = 0; i < 4; ++i) smv[buf + i * 256 + t] = xreg[i];
        __syncthreads();
        if (st < 7) {  // issue next stage's loads (hide under MFMA)
#pragma unroll
            for (int i = 0; i < 4; ++i)
                xreg[i] = Xv[xbase + (st + 1) * 1024 + i * 256 + t];
        }
        // W fragments: coalesced 16B/lane, L1/L2-hot, shared by all 4 waves
        bf16x8 A[4];
#pragma unroll
        for (int os = 0; os < 4; ++os)
            A[os] = Wv[(size_t)((ot * 8 + st) * 4 + os) * 64 + l];
        bf16x8 Bf[4];
#pragma unroll
        for (int j = 0; j < 4; ++j)
            Bf[j] = smX[buf + (w * 4 + j) * 64 + (l >> 4) * 16 + (l & 15)];
#pragma unroll
        for (int os = 0; os < 4; ++os)
#pragma unroll
            for (int j = 0; j < 4; ++j)
                acc[os][j] = __builtin_amdgcn_mfma_f32_16x16x32_bf16(A[os], Bf[j], acc[os][j], 0, 0, 0);
    }

    // epilogue (block-uniform branch on o0); all tiles fit 32KB
    if (o0 >= 320 && o0 < 576) {
        // rou -> Rt[b][n][256s] transposed, two 32-n-row halves; per-wave [32][72] bf16
        const int od = o0 - 320;
        ushort_t* Tt = (ushort_t*)sm + w * (32 * 72);
#pragma unroll
        for (int half = 0; half < 2; ++half) {
            __syncthreads();
#pragma unroll
            for (int jj = 0; jj < 2; ++jj) {
                const int j = half * 2 + jj;
#pragma unroll
                for (int os = 0; os < 4; ++os)
#pragma unroll
                    for (int r2 = 0; r2 < 4; ++r2) {
                        const int scol = os * 16 + (l >> 4) * 4 + r2;
                        const float bias = be[o0 + scol];
                        Tt[(jj * 16 + (l & 15)) * 72 + scol] = f2bf(fmaxf(acc[os][j][r2] + bias, 0.f));
                    }
            }
            __syncthreads();
#pragma unroll
            for (int p = 0; p < 4; ++p) {
                const int lrow = p * 8 + (l >> 3);
                uint4 v = *(const uint4*)&Tt[lrow * 72 + (l & 7) * 8];
                *(uint4*)&Rt[((size_t)b * N_ + n0 + w * 64 + half * 32 + lrow) * 256 + od + (l & 7) * 8] = v;
            }
        }
    } else {
        ushort_t* dst; int od, osz;
        if (o0 < 64)       { dst = Pbf; od = o0;       osz = 64;  }
        else if (o0 < 320) { dst = Tbf; od = o0 - 64;  osz = 256; }
        else               { dst = Vbf; od = o0 - 576; osz = 256; }
        ushort_t* Tw = (ushort_t*)sm + w * (32 * 68);
#pragma unroll
        for (int half = 0; half < 2; ++half) {
            __syncthreads();
#pragma unroll
            for (int osl = 0; osl < 2; ++osl) {
                const int os = half * 2 + osl;
#pragma unroll
                for (int r2 = 0; r2 < 4; ++r2) {
                    const int lrow = osl * 16 + (l >> 4) * 4 + r2;
                    const int orow = half * 32 + lrow;
                    const float bias = be[o0 + orow];
#pragma unroll
                    for (int j = 0; j < 4; ++j)
                        Tw[lrow * 68 + j * 16 + (l & 15)] = f2bf(fmaxf(acc[os][j][r2] + bias, 0.f));
                }
            }
            __syncthreads();
#pragma unroll
            for (int i = 0; i < 8; ++i) {
                const int lrow = i * 4 + (l >> 4);
                ushort4 v = *(const ushort4*)&Tw[lrow * 68 + (l & 15) * 4];
                *(ushort4*)&dst[((size_t)(b * osz + od + half * 32 + lrow)) * N_ + n0 + w * 64 + (l & 15) * 4] = v;
            }
        }
    }
}

// ---------------- theta row stats: st2[row] = (max, 1/sum(exp(x-max))) over N
__global__ __launch_bounds__(256) void rowstat_n(
    const ushort_t* __restrict__ T, float* __restrict__ st2)
{
    const int row = blockIdx.x;  // b*256 + s
    const ushort4* p = (const ushort4*)(T + (size_t)row * N_);
    const int t = threadIdx.x;
    float v[36];
    float mx = -INFINITY;
#pragma unroll
    for (int i = 0; i < 9; ++i) {
        ushort4 u = p[t + i * 256];
        v[i * 4 + 0] = bf2f(u.x); v[i * 4 + 1] = bf2f(u.y);
        v[i * 4 + 2] = bf2f(u.z); v[i * 4 + 3] = bf2f(u.w);
        mx = fmaxf(mx, fmaxf(fmaxf(v[i * 4], v[i * 4 + 1]), fmaxf(v[i * 4 + 2], v[i * 4 + 3])));
    }
    __shared__ float red[256];
    red[t] = mx; __syncthreads();
    for (int s2 = 128; s2 > 0; s2 >>= 1) {
        if (t < s2) red[t] = fmaxf(red[t], red[t + s2]);
        __syncthreads();
    }
    mx = red[0]; __syncthreads();
    float sum = 0.f;
#pragma unroll
    for (int i = 0; i < 36; ++i) sum += __expf(v[i] - mx);
    red[t] = sum; __syncthreads();
    for (int s2 = 128; s2 > 0; s2 >>= 1) {
        if (t < s2) red[t] += red[t + s2];
        __syncthreads();
    }
    if (t == 0) ((float2*)st2)[row] = make_float2(mx, 1.0f / red[0]);
}

// ---------------- softmax over contiguous rows of 256 bf16 (rou: over s at fixed n), in place
__global__ __launch_bounds__(256) void softmax_rows(ushort_t* __restrict__ R)
{
    const size_t row = (size_t)blockIdx.x * 4 + (threadIdx.x >> 6);
    const int l = threadIdx.x & 63;
    ushort4* p = (ushort4*)(R + row * 256);
    ushort4 u = p[l];
    float f0 = bf2f(u.x), f1 = bf2f(u.y), f2 = bf2f(u.z), f3 = bf2f(u.w);
    float mx = fmaxf(fmaxf(f0, f1), fmaxf(f2, f3));
#pragma unroll
    for (int m = 1; m < 64; m <<= 1) mx = fmaxf(mx, __shfl_xor(mx, m));
    f0 = __expf(f0 - mx); f1 = __expf(f1 - mx); f2 = __expf(f2 - mx); f3 = __expf(f3 - mx);
    float s = f0 + f1 + f2 + f3;
#pragma unroll
    for (int m = 1; m < 64; m <<= 1) s += __shfl_xor(s, m);
    const float inv = 1.0f / s;
    u.x = f2bf(f0 * inv); u.y = f2bf(f1 * inv); u.z = f2bf(f2 * inv); u.w = f2bf(f3 * inv);
    p[l] = u;
}

// ---------------- MFMA: P[chunk][b][k][s] = sum_{n in chunk} A[b,k,n] * w(Bm)[b,s,n]
__global__ __launch_bounds__(256) void ks_mfma(
    const ushort_t* __restrict__ A, const ushort_t* __restrict__ Bm,
    const float* __restrict__ st2, float* __restrict__ P)
{
    __shared__ short sm[32768];
    const int t = threadIdx.x;
    const int l = t & 63, w = t >> 6;
    const int chunk = blockIdx.x, b = blockIdx.y;
    const int ccell = chunk * 32;

    const uint4* Av = (const uint4*)A;
    const uint4* Bv = (const uint4*)Bm;
    const float2* S2 = (const float2*)st2;
    uint4* smv = (uint4*)sm;
    const bool doexp = (st2 != nullptr);

    uint4 wreg[8], xreg[8];
    float2 sreg[8];
#pragma unroll
    for (int i = 0; i < 8; ++i) {
        int cell = i * 256 + t;
        int osub = cell >> 9, g = (cell >> 4) & 31, oi = cell & 15;
        wreg[i] = Av[(size_t)(b * 64 + osub * 16 + oi) * NC8 + ccell + g];
    }
#pragma unroll
    for (int i = 0; i < 8; ++i) {
        int cell = i * 256 + t;
        int s = cell >> 7, g8 = (cell >> 4) & 7, ni = cell & 15;
        int row = s * 16 + ni;
        xreg[i] = Bv[(size_t)(b * 256 + row) * NC8 + ccell + g8];
        if (doexp) sreg[i] = S2[b * 256 + row];
    }
#pragma unroll
    for (int i = 0; i < 8; ++i) smv[i * 256 + t] = wreg[i];
#pragma unroll
    for (int i = 0; i < 8; ++i) smv[2048 + i * 256 + t] = doexp ? expcell(xreg[i], sreg[i]) : xreg[i];
    __syncthreads();

    f32x4 zr = {0.f, 0.f, 0.f, 0.f};
    f32x4 acc[4][4];
#pragma unroll
    for (int i = 0; i < 4; ++i)
#pragma unroll
        for (int j = 0; j < 4; ++j) acc[i][j] = zr;

    const bf16x8* smW = (const bf16x8*)sm;
    const bf16x8* smX = (const bf16x8*)(sm + 16384);

    for (int st = 0; st < 4; ++st) {
        if (st < 3) {
#pragma unroll
            for (int i = 0; i < 8; ++i) {
                int cell = i * 256 + t;
                int s = cell >> 7, g8 = (cell >> 4) & 7, ni = cell & 15;
                int row = s * 16 + ni;
                xreg[i] = Bv[(size_t)(b * 256 + row) * NC8 + ccell + (st + 1) * 8 + g8];
                if (doexp) sreg[i] = S2[b * 256 + row];
            }
        }
#pragma unroll
        for (int kgl = 0; kgl < 2; ++kgl) {
            const int kg = st * 2 + kgl;
            bf16x8 Af[4], Bf[4];
#pragma unroll
            for (int os = 0; os < 4; ++os)
                Af[os] = smW[(os * 32 + kg * 4 + (l >> 4)) * 16 + (l & 15)];
#pragma unroll
            for (int j = 0; j < 4; ++j)
                Bf[j] = smX[((w * 4 + j) * 8 + kgl * 4 + (l >> 4)) * 16 + (l & 15)];
#pragma unroll
            for (int os = 0; os < 4; ++os)
#pragma unroll
                for (int j = 0; j < 4; ++j)
                    acc[os][j] = __builtin_amdgcn_mfma_f32_16x16x32_bf16(Af[os], Bf[j], acc[os][j], 0, 0, 0);
        }
        __syncthreads();
        if (st < 3) {
#pragma unroll
            for (int i = 0; i < 8; ++i) smv[2048 + i * 256 + t] = doexp ? expcell(xreg[i], sreg[i]) : xreg[i];
            __syncthreads();
        }
    }

    float* Pb = P + ((size_t)(chunk * B_ + b)) * TILE_KS;
#pragma unroll
    for (int os = 0; os < 4; ++os)
#pragma unroll
        for (int r = 0; r < 4; ++r) {
            const int k = os * 16 + (l >> 4) * 4 + r;
#pragma unroll
            for (int j = 0; j < 4; ++j)
                Pb[k * 256 + (w * 4 + j) * 16 + (l & 15)] = acc[os][j][r];
        }
}

// ---------------- MFMA: Qraw[b][n][k] = sum_s Dbf[b,k,s] * Rsm[b,n,s]; fused nrm2 atomics
__global__ __launch_bounds__(256) void qt_mfma(
    const ushort_t* __restrict__ Dbf,  // [b][64][256]
    const ushort_t* __restrict__ Rsm,  // [b][N][256]
    float* __restrict__ Qraw,          // [b][N][64]
    float* __restrict__ Nrm)           // [b][64], pre-zeroed
{
    __shared__ short sm[32768];
    const int t = threadIdx.x;
    const int l = t & 63, w = t >> 6;
    const int b = blockIdx.x / 36;
    const int n0 = (blockIdx.x % 36) * 256;

    const uint4* Av = (const uint4*)Dbf;
    const uint4* Xv = (const uint4*)Rsm;
    uint4* smv = (uint4*)sm;

    uint4 wreg[8], xreg[8];
#pragma unroll
    for (int i = 0; i < 8; ++i) {
        int cell = i * 256 + t;
        int osub = cell >> 9, g = (cell >> 4) & 31, oi = cell & 15;
        wreg[i] = Av[(size_t)(b * 64 + osub * 16 + oi) * 32 + g];
    }
#pragma unroll
    for (int i = 0; i < 8; ++i) {
        int cell = i * 256 + t;
        int s = cell >> 7, g8 = (cell >> 4) & 7, ni = cell & 15;
        xreg[i] = Xv[((size_t)b * N_ + n0 + s * 16 + ni) * 32 + g8];
    }
#pragma unroll
    for (int i = 0; i < 8; ++i) smv[i * 256 + t] = wreg[i];
#pragma unroll
    for (int i = 0; i < 8; ++i) smv[2048 + i * 256 + t] = xreg[i];
    __syncthreads();

    f32x4 zr = {0.f, 0.f, 0.f, 0.f};
    f32x4 acc[4][4];
#pragma unroll
    for (int i = 0; i < 4; ++i)
#pragma unroll
        for (int j = 0; j < 4; ++j) acc[i][j] = zr;

    const bf16x8* smW = (const bf16x8*)sm;
    const bf16x8* smX = (const bf16x8*)(sm + 16384);

    for (int st = 0; st < 4; ++st) {
        if (st < 3) {
#pragma unroll
            for (int i = 0; i < 8; ++i) {
                int cell = i * 256 + t;
                int s = cell >> 7, g8 = (cell >> 4) & 7, ni = cell & 15;
                xreg[i] = Xv[((size_t)b * N_ + n0 + s * 16 + ni) * 32 + (st + 1) * 8 + g8];
            }
        }
#pragma unroll
        for (int kgl = 0; kgl < 2; ++kgl) {
            const int kg = st * 2 + kgl;
            bf16x8 Af[4], Bf[4];
#pragma unroll
            for (int os = 0; os < 4; ++os)
                Af[os] = smW[(os * 32 + kg * 4 + (l >> 4)) * 16 + (l & 15)];
#pragma unroll
            for (int j = 0; j < 4; ++j)
                Bf[j] = smX[((w * 4 + j) * 8 + kgl * 4 + (l >> 4)) * 16 + (l & 15)];
#pragma unroll
            for (int os = 0; os < 4; ++os)
#pragma unroll
                for (int j = 0; j < 4; ++j)
                    acc[os][j] = __builtin_amdgcn_mfma_f32_16x16x32_bf16(Af[os], Bf[j], acc[os][j], 0, 0, 0);
        }
        __syncthreads();
        if (st < 3) {
#pragma unroll
            for (int i = 0; i < 8; ++i) smv[2048 + i * 256 + t] = xreg[i];
            __syncthreads();
        }
    }

    // epilogue: nrm2 partials + [n][k] transposed fp32 stores
    float* snrm = (float*)sm + 9216;
    __syncthreads();
    if (t < 64) snrm[t] = 0.f;
    __syncthreads();
#pragma unroll
    for (int os = 0; os < 4; ++os)
#pragma unroll
        for (int r = 0; r < 4; ++r) {
            float p = 0.f;
#pragma unroll
            for (int j = 0; j < 4; ++j) p = fmaf(acc[os][j][r], acc[os][j][r], p);
#pragma unroll
            for (int m = 1; m < 16; m <<= 1) p += __shfl_xor(p, m);
            if ((l & 15) == 0) atomicAdd(&snrm[os * 16 + (l >> 4) * 4 + r], p);
        }
    float* Tw = (float*)sm + w * 2304;  // per-wave [32][72]
#pragma unroll
    for (int h = 0; h < 2; ++h) {
        __syncthreads();
#pragma unroll
        for (int os = 0; os < 4; ++os)
#pragma unroll
            for (int r = 0; r < 4; ++r) {
                const int kcol = os * 16 + (l >> 4) * 4 + r;
#pragma unroll
                for (int jj = 0; jj < 2; ++jj)
                    Tw[(jj * 16 + (l & 15)) * 72 + kcol] = acc[os][h * 2 + jj][r];
            }
        __syncthreads();
#pragma unroll
        for (int i = 0; i < 8; ++i) {
            const int lrow = i * 4 + (l >> 4);
            f32x4 v = *(const f32x4*)&Tw[lrow * 72 + (l & 15) * 4];
            *(f32x4*)&Qraw[((size_t)b * N_ + n0 + w * 64 + h * 32 + lrow) * 64 + (l & 15) * 4] = v;
        }
    }
    __syncthreads();
    if (t < 64) atomicAdd(&Nrm[b * 64 + t], snrm[t]);
}

// ---------------- partial-sum reductions over NCHUNK
__global__ __launch_bounds__(256) void chunk_reduce_bf(
    const float* __restrict__ P, ushort_t* __restrict__ outb)
{
    const int i = blockIdx.x * 256 + threadIdx.x;
    float s = 0.f;
#pragma unroll
    for (int c = 0; c < NCHUNK; ++c) s += P[(size_t)c * (B_ * TILE_KS) + i];
    outb[i] = f2bf(s);
}
__global__ __launch_bounds__(256) void chunk_reduce_f(
    const float* __restrict__ P, float* __restrict__ outf)
{
    const int i = blockIdx.x * 256 + threadIdx.x;
    float s = 0.f;
#pragma unroll
    for (int c = 0; c < NCHUNK; ++c) s += P[(size_t)c * (B_ * TILE_KS) + i];
    outf[i] = s;
}

// ---------------- Q = softmax_k(Qraw * invn); write Qout[b][n][k] fp32 + Qbf[b][k][n] bf16
__global__ __launch_bounds__(256) void q_final(
    const float* __restrict__ Qraw, const float* __restrict__ Nrm,
    float* __restrict__ Qout, ushort_t* __restrict__ Qbf)
{
    __shared__ ushort_t Tq[64 * 256];
    __shared__ float invn[64];
    const int b = blockIdx.y;
    const int n0 = blockIdx.x * 256;
    const int t = threadIdx.x;
    const int l = t & 63, w = t >> 6;
    if (t < 64) invn[t] = 1.0f / fmaxf(sqrtf(Nrm[b * 64 + t]), 1e-12f);
    __syncthreads();
    const size_t base = ((size_t)b * N_ + n0 + t) * 64;
    float q[64];
#pragma unroll
    for (int kk = 0; kk < 16; ++kk) {
        f32x4 v = *(const f32x4*)&Qraw[base + kk * 4];
        q[kk * 4 + 0] = v[0]; q[kk * 4 + 1] = v[1]; q[kk * 4 + 2] = v[2]; q[kk * 4 + 3] = v[3];
    }
    float mx = -INFINITY;
#pragma unroll
    for (int k = 0; k < 64; ++k) { q[k] *= invn[k]; mx = fmaxf(mx, q[k]); }
    float sum = 0.f;
#pragma unroll
    for (int k = 0; k < 64; ++k) { q[k] = __expf(q[k] - mx); sum += q[k]; }
    const float inv = 1.0f / sum;
#pragma unroll
    for (int kk = 0; kk < 16; ++kk) {
        f32x4 v = {q[kk * 4] * inv, q[kk * 4 + 1] * inv, q[kk * 4 + 2] * inv, q[kk * 4 + 3] * inv};
        *(f32x4*)&Qout[base + kk * 4] = v;
        q[kk * 4] = v[0]; q[kk * 4 + 1] = v[1]; q[kk * 4 + 2] = v[2]; q[kk * 4 + 3] = v[3];
    }
#pragma unroll
    for (int k = 0; k < 64; ++k) Tq[k * 256 + t] = f2bf(q[k]);
    __syncthreads();
#pragma unroll
    for (int kk = 0; kk < 16; ++kk) {
        const int k = kk * 4 + w;
        ushort4 v = *(const ushort4*)&Tq[k * 256 + l * 4];
        *(ushort4*)&Qbf[((size_t)b * 64 + k) * N_ + n0 + l * 4] = v;
    }
}

// ---------------- Z[b,s,k] = ZnT[b,k,s] / l2norm over s (qsum cancels in l2norm)
__global__ __launch_bounds__(256) void z_final(
    const float* __restrict__ ZnT, float* __restrict__ Z)
{
    __shared__ float red[256];
    __shared__ float invn[64];
    const int b = blockIdx.x;
    const int t = threadIdx.x;
    const float* Zb = ZnT + (size_t)b * TILE_KS;
    {
        const int k = t >> 2, qq = t & 3;
        float ss = 0.f;
        for (int j = 0; j < 64; ++j) {
            float v = Zb[k * 256 + qq * 64 + j];
            ss = fmaf(v, v, ss);
        }
        red[t] = ss;
    }
    __syncthreads();
    if ((t & 3) == 0) {
        float tot = red[t] + red[t + 1] + red[t + 2] + red[t + 3];
        invn[t >> 2] = 1.0f / fmaxf(sqrtf(tot), 1e-12f);
    }
    __syncthreads();
    {
        const int k = t & 63, w = t >> 6;
        const float sc = invn[k];
        for (int j = 0; j < 64; ++j) {
            int s = w * 64 + j;
            Z[((size_t)b * 256 + s) * 64 + k] = Zb[k * 256 + s] * sc;
        }
    }
}

extern "C" void kernel_launch(void* const* d_in, const int* in_sizes, int n_in,
                              void* d_out, int out_size, void* d_ws, size_t ws_size,
                              hipStream_t stream)
{
    const float* X       = (const float*)d_in[0];
    const float* phi_w   = (const float*)d_in[1];
    const float* phi_g   = (const float*)d_in[2];
    const float* phi_b   = (const float*)d_in[3];
    const float* phi_m   = (const float*)d_in[4];
    const float* phi_v   = (const float*)d_in[5];
    const float* theta_w = (const float*)d_in[6];
    const float* theta_g = (const float*)d_in[7];
    const float* theta_b = (const float*)d_in[8];
    const float* theta_m = (const float*)d_in[9];
    const float* theta_v = (const float*)d_in[10];
    const float* rou_w   = (const float*)d_in[11];
    const float* rou_g   = (const float*)d_in[12];
    const float* rou_b   = (const float*)d_in[13];
    const float* rou_m   = (const float*)d_in[14];
    const float* rou_v   = (const float*)d_in[15];
    const float* val_w   = (const float*)d_in[16];
    const float* val_g   = (const float*)d_in[17];
    const float* val_b   = (const float*)d_in[18];
    const float* val_m   = (const float*)d_in[19];
    const float* val_v   = (const float*)d_in[20];

    float* ws = (float*)d_ws;
    size_t off = 0;
    ushort_t* Xs  = (ushort_t*)(ws + off); off += (size_t)B_ * N_ * C_ / 2;
    ushort_t* Wt  = (ushort_t*)(ws + off); off += 832 * C_ / 2;
    float* be     = ws + off; off += 832;
    float* st2    = ws + off; off += 2 * B_ * 256;
    ushort_t* Pbf = (ushort_t*)(ws + off); off += (size_t)B_ * 64 * N_ / 2;
    ushort_t* Tbf = (ushort_t*)(ws + off); off += (size_t)B_ * 256 * N_ / 2;
    ushort_t* Vbf = (ushort_t*)(ws + off); off += (size_t)B_ * 256 * N_ / 2;
    ushort_t* Rt  = (ushort_t*)(ws + off); off += (size_t)B_ * N_ * 256 / 2;
    ushort_t* Qbf = (ushort_t*)(ws + off); off += (size_t)B_ * 64 * N_ / 2;
    ushort_t* Dbf = (ushort_t*)(ws + off); off += (size_t)B_ * 64 * 256 / 2;
    float* part   = ws + off; off += (size_t)NCHUNK * B_ * TILE_KS;
    float* Qraw   = ws + off; off += (size_t)B_ * N_ * 64;
    float* ZnT    = ws + off; off += (size_t)B_ * TILE_KS;
    float* Nrm    = ws + off; off += B_ * 64;

    float* Zout = (float*)d_out;                  // B*S*K
    float* Qout = Zout + (size_t)B_ * S_ * K_;    // B*N*K

    hipMemsetAsync(Nrm, 0, B_ * 64 * sizeof(float), stream);

    prep_w<<<832, 256, 0, stream>>>(phi_w, phi_g, phi_b, phi_m, phi_v,
                                    theta_w, theta_g, theta_b, theta_m, theta_v,
                                    rou_w, rou_g, rou_b, rou_m, rou_v,
                                    val_w, val_g, val_b, val_m, val_v, Wt, be);
    xpose<<<dim3(N_ / 64, C_ / 64, B_), 256, 0, stream>>>(X, Xs);

    proj_mfma_all<<<3744, 256, 0, stream>>>(Wt, be, Xs, Pbf, Tbf, Vbf, Rt);

    rowstat_n<<<B_ * 256, 256, 0, stream>>>(Tbf, st2);
    softmax_rows<<<B_ * N_ / 4, 256, 0, stream>>>(Rt);

    ks_mfma<<<dim3(NCHUNK, B_), 256, 0, stream>>>(Pbf, Tbf, st2, part);
    chunk_reduce_bf<<<B_ * TILE_KS / 256, 256, 0, stream>>>(part, Dbf);

    qt_mfma<<<36 * B_, 256, 0, stream>>>(Dbf, Rt, Qraw, Nrm);
    q_final<<<dim3(36, B_), 256, 0, stream>>>(Qraw, Nrm, Qout, Qbf);

    ks_mfma<<<dim3(NCHUNK, B_), 256, 0, stream>>>(Qbf, Vbf, (const float*)nullptr, part);
    chunk_reduce_f<<<B_ * TILE_KS / 256, 256, 0, stream>>>(part, ZnT);
    z_final<<<B_, 256, 0, stream>>>(ZnT, Zout);
}